// Round 7
// baseline (984.921 us; speedup 1.0000x reference)
//
#include <hip/hip_runtime.h>
#include <math.h>

typedef __attribute__((ext_vector_type(8))) short bf16x8_t;
typedef __attribute__((ext_vector_type(4))) float f32x4;

__device__ __forceinline__ unsigned short f2bf(float f) {
  unsigned int u = __builtin_bit_cast(unsigned int, f);
  u += 0x7FFFu + ((u >> 16) & 1u);
  return (unsigned short)(u >> 16);
}
__device__ __forceinline__ float bf2f(unsigned short h) {
  unsigned int u = ((unsigned int)h) << 16;
  return __builtin_bit_cast(float, u);
}

typedef const __attribute__((address_space(1))) void* as1cv;
typedef __attribute__((address_space(3))) void* as3v;

__device__ __forceinline__ void gld_lds16(const unsigned short* g, unsigned short* l) {
  __builtin_amdgcn_global_load_lds((as1cv)g, (as3v)l, 16, 0, 0);
}

// ---------------- t-vector projections: gvec[4][8][256] = {an_g, an_b, fn_g, fn_b} ----------------
__global__ __launch_bounds__(256) void tvec_kernel(const float* __restrict__ t,
    const float* __restrict__ an_g, const float* __restrict__ an_b,
    const float* __restrict__ fn_g, const float* __restrict__ fn_b,
    float* __restrict__ gvec) {
  int d = threadIdx.x;
  int b = blockIdx.x;      // 0..7
  int m = blockIdx.y;      // 0..3
  __shared__ float ts[256];
  ts[d] = t[b * 256 + d];
  __syncthreads();
  const float* W = (m == 0) ? an_g : (m == 1) ? an_b : (m == 2) ? fn_g : fn_b;
  float acc = 0.f;
  #pragma unroll 8
  for (int k = 0; k < 256; ++k) acc += ts[k] * W[d * 256 + k];
  gvec[(m * 8 + b) * 256 + d] = acc;
}

// ---------------- weights fp32 -> bf16 (concat: wq,wk,wv,wo,w1,w2) ----------------
__global__ __launch_bounds__(256) void wconv_kernel(const float* __restrict__ wq,
    const float* __restrict__ wk, const float* __restrict__ wv, const float* __restrict__ wo,
    const float* __restrict__ w1, const float* __restrict__ w2,
    unsigned short* __restrict__ outp) {
  int i = blockIdx.x * 256 + threadIdx.x;   // total 786432
  const float* src; int off;
  if      (i <  65536) { src = wq; off = 0; }
  else if (i < 131072) { src = wk; off = 65536; }
  else if (i < 196608) { src = wv; off = 131072; }
  else if (i < 262144) { src = wo; off = 196608; }
  else if (i < 524288) { src = w1; off = 262144; }
  else                 { src = w2; off = 524288; }
  outp[i] = f2bf(src[i - off]);
}

// ---------------- RMS-FiLM: NCHW (fp32 or bf16) -> [131072][256] bf16 (pixel-major) ----------------
// WX: also write a bf16 NCHW copy of the raw input (xbf).
template<int IS_BF, int WX>
__global__ __launch_bounds__(256) void film_kernel(const void* __restrict__ in_,
    const float* __restrict__ gvec, int gsel, unsigned short* __restrict__ outbf,
    unsigned short* __restrict__ xbf) {
  const float* inf = (const float*)in_;
  const unsigned short* inb = (const unsigned short*)in_;
  int blk = blockIdx.x;             // 2048 blocks, 64 pixels each
  int b = blk >> 8;
  int p0 = (blk & 255) << 6;
  int lane = threadIdx.x & 63;      // pixel within group (phase A)
  int cg = threadIdx.x >> 6;        // channel group 0..3
  __shared__ unsigned short vals[64][264];
  __shared__ float ssred[4][64];
  __shared__ float rinvs[64];
  size_t base = ((size_t)b << 22) + p0;
  float ss = 0.f;
  #pragma unroll 4
  for (int ci = 0; ci < 64; ++ci) {
    int c = (cg << 6) + ci;
    size_t idx = base + ((size_t)c << 14) + lane;
    float v = IS_BF ? bf2f(inb[idx]) : inf[idx];
    ss += v * v;
    unsigned short hv = f2bf(v);
    vals[lane][c] = hv;
    if (WX) xbf[idx] = hv;
  }
  ssred[cg][lane] = ss;
  __syncthreads();
  if (threadIdx.x < 64) {
    float s = ssred[0][threadIdx.x] + ssred[1][threadIdx.x] + ssred[2][threadIdx.x] + ssred[3][threadIdx.x];
    rinvs[threadIdx.x] = rsqrtf(s * (1.0f / 256.0f) + 1e-6f);
  }
  __syncthreads();
  int pix = threadIdx.x >> 2;
  int c0 = (threadIdx.x & 3) << 6;
  float rv = rinvs[pix];
  const float* gp = gvec + ((gsel * 2 + 0) * 8 + b) * 256;
  const float* bp = gvec + ((gsel * 2 + 1) * 8 + b) * 256;
  unsigned short* orow = outbf + (((size_t)b << 14) + p0 + pix) * 256 + c0;
  #pragma unroll
  for (int ch = 0; ch < 8; ++ch) {
    bf16x8_t pack;
    #pragma unroll
    for (int e = 0; e < 8; ++e) {
      int c = c0 + ch * 8 + e;
      float v = bf2f(vals[pix][c]);
      float o = gp[c] * v * rv + bp[c];
      pack[e] = (short)f2bf(o);
    }
    *(bf16x8_t*)(orow + ch * 8) = pack;
  }
}

// ---------------- bf16 GEMM: out[M][N] = A[M][K] @ Bw[N][K]^T, optional (bias+GELU) ----------------
template<int DO_GELU>
__global__ __launch_bounds__(256) void gemm_kernel(const unsigned short* __restrict__ A,
    const unsigned short* __restrict__ Bw, const float* __restrict__ bias,
    unsigned short* __restrict__ outp, int K, int N) {
  __shared__ unsigned short As[128 * 64];
  __shared__ unsigned short Bs[128 * 64];
  int tid = threadIdx.x;
  int m0 = blockIdx.x << 7;
  int n0 = blockIdx.y << 7;
  int w = tid >> 6, lane = tid & 63;
  int wm = (w >> 1) << 6, wn = (w & 1) << 6;
  f32x4 acc[4][4];
  #pragma unroll
  for (int mi = 0; mi < 4; ++mi)
    #pragma unroll
    for (int ni = 0; ni < 4; ++ni)
      acc[mi][ni] = (f32x4){0.f, 0.f, 0.f, 0.f};

  for (int k0 = 0; k0 < K; k0 += 64) {
    #pragma unroll
    for (int r2 = 0; r2 < 4; ++r2) {
      int linear = (r2 << 8) + tid;       // 0..1023 (16B chunks)
      int row = linear >> 3;
      int ch = linear & 7;
      gld_lds16(A  + (size_t)(m0 + row) * K + k0 + ch * 8, As + linear * 8);
      gld_lds16(Bw + (size_t)(n0 + row) * K + k0 + ch * 8, Bs + linear * 8);
    }
    __syncthreads();
    #pragma unroll
    for (int kk = 0; kk < 64; kk += 32) {
      bf16x8_t af[4], bq[4];
      int lr = lane & 15;
      int lk = ((lane >> 4) << 3) + kk;
      #pragma unroll
      for (int mi = 0; mi < 4; ++mi)
        af[mi] = *(const bf16x8_t*)(As + ((wm + (mi << 4) + lr) << 6) + lk);
      #pragma unroll
      for (int ni = 0; ni < 4; ++ni)
        bq[ni] = *(const bf16x8_t*)(Bs + ((wn + (ni << 4) + lr) << 6) + lk);
      #pragma unroll
      for (int mi = 0; mi < 4; ++mi)
        #pragma unroll
        for (int ni = 0; ni < 4; ++ni)
          acc[mi][ni] = __builtin_amdgcn_mfma_f32_16x16x32_bf16(af[mi], bq[ni], acc[mi][ni], 0, 0, 0);
    }
    __syncthreads();
  }
  int lr = lane & 15, lg = lane >> 4;
  #pragma unroll
  for (int mi = 0; mi < 4; ++mi) {
    #pragma unroll
    for (int ni = 0; ni < 4; ++ni) {
      int col = n0 + wn + (ni << 4) + lr;
      int row = m0 + wm + (mi << 4) + (lg << 2);
      f32x4 a = acc[mi][ni];
      #pragma unroll
      for (int i = 0; i < 4; ++i) {
        float v = a[i];
        if (DO_GELU) {
          v += bias[col];
          v = 0.5f * v * (1.0f + erff(v * 0.70710678118654752f));
        }
        outp[(size_t)(row + i) * N + col] = f2bf(v);
      }
    }
  }
}

// ---------------- fused QKV projection: B = wbf rows 0..767 (wq|wk|wv) ----------------
// cols 0..255 -> q pixel-major; 256..511 -> k pixel-major; 512..767 -> v NCHW bf16 (transposed epilogue)
__global__ __launch_bounds__(256) void gemm_qkv_kernel(const unsigned short* __restrict__ A,
    const unsigned short* __restrict__ Bw, unsigned short* __restrict__ outq,
    unsigned short* __restrict__ outk, unsigned short* __restrict__ outvt) {
  __shared__ unsigned short smem[16384];   // As(16K) | Bs(16K); reused as stg[128][128] for v
  unsigned short* As = smem;
  unsigned short* Bs = smem + 8192;
  const int K = 256;
  int tid = threadIdx.x;
  int m0 = blockIdx.x << 7;
  int n0 = blockIdx.y << 7;              // 0..640
  int w = tid >> 6, lane = tid & 63;
  int wm = (w >> 1) << 6, wn = (w & 1) << 6;
  f32x4 acc[4][4];
  #pragma unroll
  for (int mi = 0; mi < 4; ++mi)
    #pragma unroll
    for (int ni = 0; ni < 4; ++ni)
      acc[mi][ni] = (f32x4){0.f, 0.f, 0.f, 0.f};

  for (int k0 = 0; k0 < K; k0 += 64) {
    #pragma unroll
    for (int r2 = 0; r2 < 4; ++r2) {
      int linear = (r2 << 8) + tid;
      int row = linear >> 3;
      int ch = linear & 7;
      gld_lds16(A  + (size_t)(m0 + row) * K + k0 + ch * 8, As + linear * 8);
      gld_lds16(Bw + (size_t)(n0 + row) * K + k0 + ch * 8, Bs + linear * 8);
    }
    __syncthreads();
    #pragma unroll
    for (int kk = 0; kk < 64; kk += 32) {
      bf16x8_t af[4], bq[4];
      int lr = lane & 15;
      int lk = ((lane >> 4) << 3) + kk;
      #pragma unroll
      for (int mi = 0; mi < 4; ++mi)
        af[mi] = *(const bf16x8_t*)(As + ((wm + (mi << 4) + lr) << 6) + lk);
      #pragma unroll
      for (int ni = 0; ni < 4; ++ni)
        bq[ni] = *(const bf16x8_t*)(Bs + ((wn + (ni << 4) + lr) << 6) + lk);
      #pragma unroll
      for (int mi = 0; mi < 4; ++mi)
        #pragma unroll
        for (int ni = 0; ni < 4; ++ni)
          acc[mi][ni] = __builtin_amdgcn_mfma_f32_16x16x32_bf16(af[mi], bq[ni], acc[mi][ni], 0, 0, 0);
    }
    __syncthreads();
  }

  int lr = lane & 15, lg = lane >> 4;
  if (n0 < 512) {
    // direct pixel-major write to q or k
    unsigned short* dst = (n0 < 256) ? outq : outk;
    #pragma unroll
    for (int mi = 0; mi < 4; ++mi) {
      #pragma unroll
      for (int ni = 0; ni < 4; ++ni) {
        int col = (n0 & 255) + wn + (ni << 4) + lr;
        int row = m0 + wm + (mi << 4) + (lg << 2);
        f32x4 a = acc[mi][ni];
        #pragma unroll
        for (int i = 0; i < 4; ++i)
          dst[(size_t)(row + i) * 256 + col] = f2bf(a[i]);
      }
    }
  } else {
    // transposed (NCHW) epilogue for v
    #pragma unroll
    for (int mi = 0; mi < 4; ++mi)
      #pragma unroll
      for (int ni = 0; ni < 4; ++ni) {
        int cl = wn + (ni << 4) + lr;
        int rl = wm + (mi << 4) + (lg << 2);
        f32x4 a = acc[mi][ni];
        #pragma unroll
        for (int i = 0; i < 4; ++i)
          smem[cl * 128 + rl + i] = f2bf(a[i]);
      }
    __syncthreads();
    int cl = tid >> 1;
    int half = tid & 1;
    int b = m0 >> 14;
    int pix = (m0 & 16383) + half * 64;
    int c = (n0 - 512) + cl;
    const unsigned short* srow = smem + cl * 128 + half * 64;
    unsigned short* orow = outvt + ((size_t)b * 256 + c) * 16384 + pix;
    #pragma unroll
    for (int jj = 0; jj < 8; ++jj)
      *(bf16x8_t*)(orow + jj * 8) = *(const bf16x8_t*)(srow + jj * 8);
  }
}

// ---------------- WO fused: x1_nchw_bf16 = xbf + o@wo^T + wo_b  (K=256, N=256) ----------------
__global__ __launch_bounds__(256) void gemm_wof_kernel(const unsigned short* __restrict__ A,
    const unsigned short* __restrict__ Bw, const float* __restrict__ bias,
    const unsigned short* __restrict__ xbf, unsigned short* __restrict__ outp) {
  __shared__ unsigned short smem[16384];
  unsigned short* As = smem;
  unsigned short* Bs = smem + 8192;
  const int K = 256;
  int tid = threadIdx.x;
  int m0 = blockIdx.x << 7;
  int n0 = blockIdx.y << 7;
  int w = tid >> 6, lane = tid & 63;
  int wm = (w >> 1) << 6, wn = (w & 1) << 6;
  f32x4 acc[4][4];
  #pragma unroll
  for (int mi = 0; mi < 4; ++mi)
    #pragma unroll
    for (int ni = 0; ni < 4; ++ni)
      acc[mi][ni] = (f32x4){0.f, 0.f, 0.f, 0.f};

  for (int k0 = 0; k0 < K; k0 += 64) {
    #pragma unroll
    for (int r2 = 0; r2 < 4; ++r2) {
      int linear = (r2 << 8) + tid;
      int row = linear >> 3;
      int ch = linear & 7;
      gld_lds16(A  + (size_t)(m0 + row) * K + k0 + ch * 8, As + linear * 8);
      gld_lds16(Bw + (size_t)(n0 + row) * K + k0 + ch * 8, Bs + linear * 8);
    }
    __syncthreads();
    #pragma unroll
    for (int kk = 0; kk < 64; kk += 32) {
      bf16x8_t af[4], bq[4];
      int lr = lane & 15;
      int lk = ((lane >> 4) << 3) + kk;
      #pragma unroll
      for (int mi = 0; mi < 4; ++mi)
        af[mi] = *(const bf16x8_t*)(As + ((wm + (mi << 4) + lr) << 6) + lk);
      #pragma unroll
      for (int ni = 0; ni < 4; ++ni)
        bq[ni] = *(const bf16x8_t*)(Bs + ((wn + (ni << 4) + lr) << 6) + lk);
      #pragma unroll
      for (int mi = 0; mi < 4; ++mi)
        #pragma unroll
        for (int ni = 0; ni < 4; ++ni)
          acc[mi][ni] = __builtin_amdgcn_mfma_f32_16x16x32_bf16(af[mi], bq[ni], acc[mi][ni], 0, 0, 0);
    }
    __syncthreads();
  }

  // stage transposed: stg[col_local][row_local]
  int lr = lane & 15, lg = lane >> 4;
  #pragma unroll
  for (int mi = 0; mi < 4; ++mi)
    #pragma unroll
    for (int ni = 0; ni < 4; ++ni) {
      int cl = wn + (ni << 4) + lr;
      int rl = wm + (mi << 4) + (lg << 2);
      f32x4 a = acc[mi][ni];
      #pragma unroll
      for (int i = 0; i < 4; ++i)
        smem[cl * 128 + rl + i] = f2bf(a[i]);
    }
  __syncthreads();

  int cl = tid >> 1;
  int half = tid & 1;
  int b = m0 >> 14;
  int pix = (m0 & 16383) + half * 64;
  int c = n0 + cl;
  const unsigned short* srow = smem + cl * 128 + half * 64;
  size_t gbase = ((size_t)b * 256 + c) * 16384 + pix;
  const unsigned short* xrow = xbf + gbase;
  unsigned short* orow = outp + gbase;
  float bb = bias[c];
  #pragma unroll
  for (int jj = 0; jj < 8; ++jj) {
    bf16x8_t sv = *(const bf16x8_t*)(srow + jj * 8);
    bf16x8_t xv = *(const bf16x8_t*)(xrow + jj * 8);
    bf16x8_t ov;
    #pragma unroll
    for (int e = 0; e < 8; ++e)
      ov[e] = (short)f2bf(bf2f((unsigned short)sv[e]) + bf2f((unsigned short)xv[e]) + bb);
    *(bf16x8_t*)(orow + jj * 8) = ov;
  }
}

// ---------------- MLP2 fused: out_nchw = x1 + hmid@w2^T + b2  (K=1024, N=256) ----------------
__global__ __launch_bounds__(256) void gemm2f_kernel(const unsigned short* __restrict__ A,
    const unsigned short* __restrict__ Bw, const float* __restrict__ bias,
    const unsigned short* __restrict__ x1, float* __restrict__ outp, int m_base) {
  __shared__ unsigned short smem[16384];   // 32 KiB: As(16K) | Bs(16K), reused as stg[128][128]
  unsigned short* As = smem;
  unsigned short* Bs = smem + 8192;
  const int K = 1024, N = 256;
  int tid = threadIdx.x;
  int m0 = blockIdx.x << 7;
  int n0 = blockIdx.y << 7;
  int w = tid >> 6, lane = tid & 63;
  int wm = (w >> 1) << 6, wn = (w & 1) << 6;
  f32x4 acc[4][4];
  #pragma unroll
  for (int mi = 0; mi < 4; ++mi)
    #pragma unroll
    for (int ni = 0; ni < 4; ++ni)
      acc[mi][ni] = (f32x4){0.f, 0.f, 0.f, 0.f};

  for (int k0 = 0; k0 < K; k0 += 64) {
    #pragma unroll
    for (int r2 = 0; r2 < 4; ++r2) {
      int linear = (r2 << 8) + tid;
      int row = linear >> 3;
      int ch = linear & 7;
      gld_lds16(A  + (size_t)(m0 + row) * K + k0 + ch * 8, As + linear * 8);
      gld_lds16(Bw + (size_t)(n0 + row) * K + k0 + ch * 8, Bs + linear * 8);
    }
    __syncthreads();
    #pragma unroll
    for (int kk = 0; kk < 64; kk += 32) {
      bf16x8_t af[4], bq[4];
      int lr = lane & 15;
      int lk = ((lane >> 4) << 3) + kk;
      #pragma unroll
      for (int mi = 0; mi < 4; ++mi)
        af[mi] = *(const bf16x8_t*)(As + ((wm + (mi << 4) + lr) << 6) + lk);
      #pragma unroll
      for (int ni = 0; ni < 4; ++ni)
        bq[ni] = *(const bf16x8_t*)(Bs + ((wn + (ni << 4) + lr) << 6) + lk);
      #pragma unroll
      for (int mi = 0; mi < 4; ++mi)
        #pragma unroll
        for (int ni = 0; ni < 4; ++ni)
          acc[mi][ni] = __builtin_amdgcn_mfma_f32_16x16x32_bf16(af[mi], bq[ni], acc[mi][ni], 0, 0, 0);
    }
    __syncthreads();
  }

  // stage transposed: stg[col_local][row_local], 128x128 bf16 = 32 KiB
  int lr = lane & 15, lg = lane >> 4;
  #pragma unroll
  for (int mi = 0; mi < 4; ++mi)
    #pragma unroll
    for (int ni = 0; ni < 4; ++ni) {
      int cl = wn + (ni << 4) + lr;
      int rl = wm + (mi << 4) + (lg << 2);
      f32x4 a = acc[mi][ni];
      #pragma unroll
      for (int i = 0; i < 4; ++i)
        smem[cl * 128 + rl + i] = f2bf(a[i]);
    }
  __syncthreads();

  // write out: thread -> (col_local = tid>>1, 64-pixel half)
  int cl = tid >> 1;
  int half = tid & 1;
  int pglob0 = m_base + m0;            // multiple of 128; whole block same image b
  int b = pglob0 >> 14;
  int pix = (pglob0 & 16383) + half * 64;
  int c = n0 + cl;
  const unsigned short* srow = smem + cl * 128 + half * 64;
  size_t gbase = ((size_t)b * 256 + c) * 16384 + pix;
  const unsigned short* xrow = x1 + gbase;
  float* orow = outp + gbase;
  float bb = bias[c];
  #pragma unroll
  for (int jj = 0; jj < 8; ++jj) {
    bf16x8_t sv = *(const bf16x8_t*)(srow + jj * 8);
    bf16x8_t xv = *(const bf16x8_t*)(xrow + jj * 8);
    #pragma unroll
    for (int e = 0; e < 8; ++e)
      orow[jj * 8 + e] = bf2f((unsigned short)sv[e]) + bf2f((unsigned short)xv[e]) + bb;
  }
}

// ---------------- MFMA windowed attention: one window per block, 4 waves, 2 heads/wave ----------------
// qt-sliced: per 16-row q-slice do S -> softmax -> PV, so the P LDS bounce is only [16][72]/wave.
// q,k pixel-major [pix][256]; v NCHW bf16 [(b*256+ch)][16384]; o pixel-major [pix][256]
__global__ __launch_bounds__(256, 4) void attn_kernel(const unsigned short* __restrict__ qg,
    const unsigned short* __restrict__ kg, const unsigned short* __restrict__ vt,
    const float* __restrict__ rpb, unsigned short* __restrict__ og) {
  __shared__ float rpbf[1800];
  __shared__ unsigned short pbuf[4][16 * 72];
  // XCD-bijective swizzle: 2048 blocks, 8 XCDs -> each image (256 windows) on one XCD.
  int wi = (blockIdx.x & 7) * 256 + (blockIdx.x >> 3);
  int b = wi >> 8, wh = (wi >> 4) & 15, ww = wi & 15;
  int tid = threadIdx.x;
  int w = tid >> 6, lane = tid & 63;
  int g = lane >> 4, lr = lane & 15;
  for (int idx = tid; idx < 1800; idx += 256) rpbf[idx] = rpb[idx];
  __syncthreads();

  int rowpix = (wh * 8) * 128 + ww * 8;           // within-image pixel of token 0
  size_t ibase = ((size_t)b << 14) + rowpix;       // global pixel index of token 0
  unsigned short* pb = pbuf[w];
  const float scale = 0.17677669529663689f;        // 1/sqrt(32)

  #pragma unroll 1
  for (int hh = 0; hh < 2; ++hh) {
    int h = w * 2 + hh;
    // ---- load Q,K fragments and hoist V fragments ----
    bf16x8_t qf[4], kf[4];
    #pragma unroll
    for (int t = 0; t < 4; ++t) {
      size_t tok = ibase + (size_t)(t * 2 + (lr >> 3)) * 128 + (lr & 7);
      qf[t] = *(const bf16x8_t*)(qg + tok * 256 + h * 32 + g * 8);
      kf[t] = *(const bf16x8_t*)(kg + tok * 256 + h * 32 + g * 8);
    }
    bf16x8_t vfr[2][2];
    #pragma unroll
    for (int ks = 0; ks < 2; ++ks)
      #pragma unroll
      for (int dt = 0; dt < 2; ++dt) {
        size_t plane = (size_t)b * 256 + h * 32 + dt * 16 + lr;
        vfr[ks][dt] = *(const bf16x8_t*)(vt + (plane << 14) + rowpix + (size_t)(ks * 4 + g) * 128);
      }
    const float* rb = &rpbf[h * 225];

    #pragma unroll 1
    for (int qt = 0; qt < 4; ++qt) {
      // ---- S slice = Q[qt] K^T (4 MFMA) ----
      f32x4 sacc[4];
      #pragma unroll
      for (int kt = 0; kt < 4; ++kt)
        sacc[kt] = __builtin_amdgcn_mfma_f32_16x16x32_bf16(qf[qt], kf[kt],
                     (f32x4){0.f, 0.f, 0.f, 0.f}, 0, 0, 0);
      // ---- softmax rows q = qt*16 + g*4 + i ----
      float sums[4];
      #pragma unroll
      for (int i = 0; i < 4; ++i) {
        int q = qt * 16 + g * 4 + i;
        int il = q >> 3, jl = q & 7;
        float v[4];
        #pragma unroll
        for (int kt = 0; kt < 4; ++kt) {
          int kv = kt * 16 + lr;
          v[kt] = sacc[kt][i] * scale + rb[(il - (kv >> 3) + 7) * 15 + (jl - (kv & 7) + 7)];
        }
        float mx = fmaxf(fmaxf(v[0], v[1]), fmaxf(v[2], v[3]));
        mx = fmaxf(mx, __shfl_xor(mx, 1));
        mx = fmaxf(mx, __shfl_xor(mx, 2));
        mx = fmaxf(mx, __shfl_xor(mx, 4));
        mx = fmaxf(mx, __shfl_xor(mx, 8));
        float sm = 0.f;
        #pragma unroll
        for (int kt = 0; kt < 4; ++kt) { v[kt] = __expf(v[kt] - mx); sm += v[kt]; }
        sm += __shfl_xor(sm, 1);
        sm += __shfl_xor(sm, 2);
        sm += __shfl_xor(sm, 4);
        sm += __shfl_xor(sm, 8);
        sums[i] = sm;
        #pragma unroll
        for (int kt = 0; kt < 4; ++kt)
          pb[(g * 4 + i) * 72 + kt * 16 + lr] = f2bf(v[kt]);
      }
      // ---- PV slice (4 MFMA); same-wave LDS dependency, no barrier ----
      f32x4 oacc[2] = {(f32x4){0.f, 0.f, 0.f, 0.f}, (f32x4){0.f, 0.f, 0.f, 0.f}};
      #pragma unroll
      for (int ks = 0; ks < 2; ++ks) {
        bf16x8_t pf = *(const bf16x8_t*)(pb + lr * 72 + ks * 32 + g * 8);
        oacc[0] = __builtin_amdgcn_mfma_f32_16x16x32_bf16(pf, vfr[ks][0], oacc[0], 0, 0, 0);
        oacc[1] = __builtin_amdgcn_mfma_f32_16x16x32_bf16(pf, vfr[ks][1], oacc[1], 0, 0, 0);
      }
      // ---- epilogue rows ----
      #pragma unroll
      for (int i = 0; i < 4; ++i) {
        int q = qt * 16 + g * 4 + i;
        float inv = 1.0f / sums[i];
        size_t tok = ibase + (size_t)(q >> 3) * 128 + (q & 7);
        unsigned int packed0 = f2bf(oacc[0][i] * inv);
        unsigned int packed1 = f2bf(oacc[1][i] * inv);
        og[tok * 256 + h * 32 + lr] = (unsigned short)packed0;
        og[tok * 256 + h * 32 + 16 + lr] = (unsigned short)packed1;
      }
    }
  }
}

// ---------------- depthwise 7x7 conv (bf16 in/out, fp32 math), pad 3, + bias ----------------
__global__ __launch_bounds__(256) void dwconv_kernel(const unsigned short* __restrict__ x1,
    const float* __restrict__ w, const float* __restrict__ bias, unsigned short* __restrict__ outp) {
  int bc = blockIdx.y;                  // 0..2047 (b*256 + c)
  int c = bc & 255;
  int y0 = blockIdx.x << 6;             // 0 or 64
  __shared__ unsigned short tile[70 * 144];   // LDS col = gx + 8; valid cols 5..138
  __shared__ float wf[49];
  const unsigned short* plane = x1 + ((size_t)bc << 14);
  int tid = threadIdx.x;

  for (int idx = tid; idx < 70 * 16; idx += 256) {
    int row = idx >> 4, ch = idx & 15;
    int gy = y0 - 3 + row;
    bf16x8_t v = (bf16x8_t){0, 0, 0, 0, 0, 0, 0, 0};
    if (gy >= 0 && gy < 128) v = *(const bf16x8_t*)(plane + gy * 128 + ch * 8);
    *(bf16x8_t*)(&tile[row * 144 + 8 + ch * 8]) = v;
  }
  for (int idx = tid; idx < 70 * 6; idx += 256) {
    int row = idx / 6, e = idx % 6;
    int col = (e < 3) ? (5 + e) : (133 + e);
    tile[row * 144 + col] = 0;
  }
  if (tid < 49) wf[tid] = w[c * 49 + tid];
  __syncthreads();

  int r = tid >> 2;                     // output row 0..63
  int c0 = (tid & 3) << 5;              // output col group: 0,32,64,96
  float acc[32];
  float bb = bias[c];
  #pragma unroll
  for (int i = 0; i < 32; ++i) acc[i] = bb;

  #pragma unroll
  for (int u = 0; u < 7; ++u) {
    const unsigned short* rowp = &tile[(r + u) * 144 + c0];
    float f[48];
    #pragma unroll
    for (int k = 0; k < 6; ++k) {
      bf16x8_t v = *(const bf16x8_t*)(rowp + k * 8);
      #pragma unroll
      for (int e = 0; e < 8; ++e) f[k * 8 + e] = bf2f((unsigned short)v[e]);
    }
    #pragma unroll
    for (int t = 0; t < 7; ++t) {
      float wv = wf[u * 7 + t];
      #pragma unroll
      for (int i = 0; i < 32; ++i) acc[i] += f[i + 5 + t] * wv;
    }
  }

  unsigned short* orow = outp + ((size_t)bc << 14) + (size_t)(y0 + r) * 128 + c0;
  #pragma unroll
  for (int k = 0; k < 4; ++k) {
    bf16x8_t v;
    #pragma unroll
    for (int e = 0; e < 8; ++e) v[e] = (short)f2bf(acc[k * 8 + e]);
    *(bf16x8_t*)(orow + k * 8) = v;
  }
}

extern "C" void kernel_launch(void* const* d_in, const int* in_sizes, int n_in,
                              void* d_out, int out_size, void* d_ws, size_t ws_size,
                              hipStream_t stream) {
  const float* x    = (const float*)d_in[0];
  const float* t    = (const float*)d_in[1];
  const float* an_g = (const float*)d_in[2];
  const float* an_b = (const float*)d_in[3];
  const float* wq   = (const float*)d_in[4];
  const float* wk   = (const float*)d_in[5];
  const float* wv   = (const float*)d_in[6];
  const float* wo_w = (const float*)d_in[7];
  const float* wo_b = (const float*)d_in[8];
  const float* rpb  = (const float*)d_in[9];
  const float* dw_w = (const float*)d_in[10];
  const float* dw_b = (const float*)d_in[11];
  const float* fn_g = (const float*)d_in[12];
  const float* fn_b = (const float*)d_in[13];
  const float* w1   = (const float*)d_in[14];
  const float* b1   = (const float*)d_in[15];
  const float* w2   = (const float*)d_in[16];
  const float* b2   = (const float*)d_in[17];
  float* outp = (float*)d_out;

  char* ws = (char*)d_ws;
  const size_t MB = 1024ull * 1024ull;
  float* gvec = (float*)ws;                                   // 32 KB
  unsigned short* wbf = (unsigned short*)(ws + 32768);        // 1.5 MiB
  unsigned short* P = (unsigned short*)(ws + 2 * MB);         // 64 MiB: y -> o -> z
  unsigned short* Q = (unsigned short*)(ws + 66 * MB);        // 64 MiB: q -> y2 -> hmid
  unsigned short* R = (unsigned short*)(ws + 130 * MB);       // 64 MiB: k -> x1 (persists)
  // total ws use: 194 MiB
  // d_out (128 MiB) scratch regions, both dead before the final MLP2 sweep rewrites d_out:
  unsigned short* xbf  = (unsigned short*)d_out;                      // [0,64) MiB bf16 copy of x (dead after WO)
  unsigned short* vbuf = (unsigned short*)((char*)d_out + 64 * MB);   // [64,128) MiB v NCHW bf16 (dead after attn)

  unsigned short* wo_bf = wbf + 196608;
  unsigned short* w1_bf = wbf + 262144;
  unsigned short* w2_bf = wbf + 524288;

  tvec_kernel<<<dim3(8, 4), 256, 0, stream>>>(t, an_g, an_b, fn_g, fn_b, gvec);
  wconv_kernel<<<3072, 256, 0, stream>>>(wq, wk, wv, wo_w, w1, w2, wbf);

  // y = rms_film(x) -> P ; also xbf = bf16(x) NCHW
  film_kernel<0, 1><<<2048, 256, 0, stream>>>(x, gvec, 0, P, xbf);

  // fused q,k,v projection (q,k pixel-major; v NCHW bf16)
  gemm_qkv_kernel<<<dim3(1024, 6), 256, 0, stream>>>(P, wbf, Q, R, vbuf);

  // windowed attention (MFMA) -> o (P; y dead)
  attn_kernel<<<2048, 256, 0, stream>>>(Q, R, vbuf, rpb, P);

  // WO fused: x1 = bf16(xbf + o@wo^T + wo_b) NCHW -> R (k dead)
  gemm_wof_kernel<<<dim3(1024, 2), 256, 0, stream>>>(P, wo_bf, wo_b, xbf, R);

  // convnext: dwconv (x1 -> y2 in Q) -> film2 (-> z in P)
  dwconv_kernel<<<dim3(2, 2048), 256, 0, stream>>>(R, dw_w, dw_b, Q);
  film_kernel<1, 0><<<2048, 256, 0, stream>>>(Q, gvec, 1, P, nullptr);

  // MLP in 4 M-quarters: hmid (Q, 64 MiB) then fused MLP2 + residual -> d_out
  for (int qtr = 0; qtr < 4; ++qtr) {
    int m_base = qtr * 32768;
    gemm_kernel<1><<<dim3(256, 8), 256, 0, stream>>>(P + (size_t)m_base * 256, w1_bf, b1, Q, 256, 1024);
    gemm2f_kernel<<<dim3(256, 2), 256, 0, stream>>>(Q, w2_bf, b2, R, outp, m_base);
  }
}

// Round 8
// 891.858 us; speedup vs baseline: 1.1043x; 1.1043x over previous
//
#include <hip/hip_runtime.h>
#include <math.h>

typedef __attribute__((ext_vector_type(8))) short bf16x8_t;
typedef __attribute__((ext_vector_type(4))) float f32x4;

__device__ __forceinline__ unsigned short f2bf(float f) {
  unsigned int u = __builtin_bit_cast(unsigned int, f);
  u += 0x7FFFu + ((u >> 16) & 1u);
  return (unsigned short)(u >> 16);
}
__device__ __forceinline__ float bf2f(unsigned short h) {
  unsigned int u = ((unsigned int)h) << 16;
  return __builtin_bit_cast(float, u);
}

typedef const __attribute__((address_space(1))) void* as1cv;
typedef __attribute__((address_space(3))) void* as3v;

__device__ __forceinline__ void gld_lds16(const unsigned short* g, unsigned short* l) {
  __builtin_amdgcn_global_load_lds((as1cv)g, (as3v)l, 16, 0, 0);
}

// ---------------- t-vector projections: gvec[4][8][256] = {an_g, an_b, fn_g, fn_b} ----------------
__global__ __launch_bounds__(256) void tvec_kernel(const float* __restrict__ t,
    const float* __restrict__ an_g, const float* __restrict__ an_b,
    const float* __restrict__ fn_g, const float* __restrict__ fn_b,
    float* __restrict__ gvec) {
  int d = threadIdx.x;
  int b = blockIdx.x;      // 0..7
  int m = blockIdx.y;      // 0..3
  __shared__ float ts[256];
  ts[d] = t[b * 256 + d];
  __syncthreads();
  const float* W = (m == 0) ? an_g : (m == 1) ? an_b : (m == 2) ? fn_g : fn_b;
  float acc = 0.f;
  #pragma unroll 8
  for (int k = 0; k < 256; ++k) acc += ts[k] * W[d * 256 + k];
  gvec[(m * 8 + b) * 256 + d] = acc;
}

// ---------------- weights fp32 -> bf16 (concat: wq,wk,wv,wo,w1,w2) ----------------
__global__ __launch_bounds__(256) void wconv_kernel(const float* __restrict__ wq,
    const float* __restrict__ wk, const float* __restrict__ wv, const float* __restrict__ wo,
    const float* __restrict__ w1, const float* __restrict__ w2,
    unsigned short* __restrict__ outp) {
  int i = blockIdx.x * 256 + threadIdx.x;   // total 786432
  const float* src; int off;
  if      (i <  65536) { src = wq; off = 0; }
  else if (i < 131072) { src = wk; off = 65536; }
  else if (i < 196608) { src = wv; off = 131072; }
  else if (i < 262144) { src = wo; off = 196608; }
  else if (i < 524288) { src = w1; off = 262144; }
  else                 { src = w2; off = 524288; }
  outp[i] = f2bf(src[i - off]);
}

// ---------------- RMS-FiLM: NCHW (fp32 or bf16) -> [131072][256] bf16 (pixel-major) ----------------
// WX: also write a bf16 NCHW copy of the raw input (xbf).
template<int IS_BF, int WX>
__global__ __launch_bounds__(256) void film_kernel(const void* __restrict__ in_,
    const float* __restrict__ gvec, int gsel, unsigned short* __restrict__ outbf,
    unsigned short* __restrict__ xbf) {
  const float* inf = (const float*)in_;
  const unsigned short* inb = (const unsigned short*)in_;
  int blk = blockIdx.x;             // 2048 blocks, 64 pixels each
  int b = blk >> 8;
  int p0 = (blk & 255) << 6;
  int lane = threadIdx.x & 63;      // pixel within group (phase A)
  int cg = threadIdx.x >> 6;        // channel group 0..3
  __shared__ unsigned short vals[64][264];
  __shared__ float ssred[4][64];
  __shared__ float rinvs[64];
  size_t base = ((size_t)b << 22) + p0;
  float ss = 0.f;
  #pragma unroll 4
  for (int ci = 0; ci < 64; ++ci) {
    int c = (cg << 6) + ci;
    size_t idx = base + ((size_t)c << 14) + lane;
    float v = IS_BF ? bf2f(inb[idx]) : inf[idx];
    ss += v * v;
    unsigned short hv = f2bf(v);
    vals[lane][c] = hv;
    if (WX) xbf[idx] = hv;
  }
  ssred[cg][lane] = ss;
  __syncthreads();
  if (threadIdx.x < 64) {
    float s = ssred[0][threadIdx.x] + ssred[1][threadIdx.x] + ssred[2][threadIdx.x] + ssred[3][threadIdx.x];
    rinvs[threadIdx.x] = rsqrtf(s * (1.0f / 256.0f) + 1e-6f);
  }
  __syncthreads();
  int pix = threadIdx.x >> 2;
  int c0 = (threadIdx.x & 3) << 6;
  float rv = rinvs[pix];
  const float* gp = gvec + ((gsel * 2 + 0) * 8 + b) * 256;
  const float* bp = gvec + ((gsel * 2 + 1) * 8 + b) * 256;
  unsigned short* orow = outbf + (((size_t)b << 14) + p0 + pix) * 256 + c0;
  #pragma unroll
  for (int ch = 0; ch < 8; ++ch) {
    bf16x8_t pack;
    #pragma unroll
    for (int e = 0; e < 8; ++e) {
      int c = c0 + ch * 8 + e;
      float v = bf2f(vals[pix][c]);
      float o = gp[c] * v * rv + bp[c];
      pack[e] = (short)f2bf(o);
    }
    *(bf16x8_t*)(orow + ch * 8) = pack;
  }
}

// ---------------- bf16 GEMM: out[M][N] = A[M][K] @ Bw[N][K]^T ----------------
template<int DO_GELU>
__global__ __launch_bounds__(256) void gemm_kernel(const unsigned short* __restrict__ A,
    const unsigned short* __restrict__ Bw, const float* __restrict__ bias,
    unsigned short* __restrict__ outp, int K, int N) {
  __shared__ unsigned short As[128 * 64];
  __shared__ unsigned short Bs[128 * 64];
  int tid = threadIdx.x;
  int m0 = blockIdx.x << 7;
  int n0 = blockIdx.y << 7;
  int w = tid >> 6, lane = tid & 63;
  int wm = (w >> 1) << 6, wn = (w & 1) << 6;
  f32x4 acc[4][4];
  #pragma unroll
  for (int mi = 0; mi < 4; ++mi)
    #pragma unroll
    for (int ni = 0; ni < 4; ++ni)
      acc[mi][ni] = (f32x4){0.f, 0.f, 0.f, 0.f};

  for (int k0 = 0; k0 < K; k0 += 64) {
    #pragma unroll
    for (int r2 = 0; r2 < 4; ++r2) {
      int linear = (r2 << 8) + tid;       // 0..1023 (16B chunks)
      int row = linear >> 3;
      int ch = linear & 7;
      gld_lds16(A  + (size_t)(m0 + row) * K + k0 + ch * 8, As + linear * 8);
      gld_lds16(Bw + (size_t)(n0 + row) * K + k0 + ch * 8, Bs + linear * 8);
    }
    __syncthreads();
    #pragma unroll
    for (int kk = 0; kk < 64; kk += 32) {
      bf16x8_t af[4], bq[4];
      int lr = lane & 15;
      int lk = ((lane >> 4) << 3) + kk;
      #pragma unroll
      for (int mi = 0; mi < 4; ++mi)
        af[mi] = *(const bf16x8_t*)(As + ((wm + (mi << 4) + lr) << 6) + lk);
      #pragma unroll
      for (int ni = 0; ni < 4; ++ni)
        bq[ni] = *(const bf16x8_t*)(Bs + ((wn + (ni << 4) + lr) << 6) + lk);
      #pragma unroll
      for (int mi = 0; mi < 4; ++mi)
        #pragma unroll
        for (int ni = 0; ni < 4; ++ni)
          acc[mi][ni] = __builtin_amdgcn_mfma_f32_16x16x32_bf16(af[mi], bq[ni], acc[mi][ni], 0, 0, 0);
    }
    __syncthreads();
  }
  int lr = lane & 15, lg = lane >> 4;
  #pragma unroll
  for (int mi = 0; mi < 4; ++mi) {
    #pragma unroll
    for (int ni = 0; ni < 4; ++ni) {
      int col = n0 + wn + (ni << 4) + lr;
      int row = m0 + wm + (mi << 4) + (lg << 2);
      f32x4 a = acc[mi][ni];
      #pragma unroll
      for (int i = 0; i < 4; ++i) {
        float v = a[i];
        if (DO_GELU) {
          v += bias[col];
          v = 0.5f * v * (1.0f + erff(v * 0.70710678118654752f));
        }
        outp[(size_t)(row + i) * N + col] = f2bf(v);
      }
    }
  }
}

// ---------------- V projection with NCHW bf16 output: vt[(b*256+col)*16384 + pix] ----------------
__global__ __launch_bounds__(256) void gemm_t_kernel(const unsigned short* __restrict__ A,
    const unsigned short* __restrict__ Bw, unsigned short* __restrict__ outp) {
  __shared__ unsigned short smem[16384];   // As(16K) | Bs(16K), reused as stg[128][128]
  unsigned short* As = smem;
  unsigned short* Bs = smem + 8192;
  const int K = 256;
  int tid = threadIdx.x;
  int m0 = blockIdx.x << 7;
  int n0 = blockIdx.y << 7;
  int w = tid >> 6, lane = tid & 63;
  int wm = (w >> 1) << 6, wn = (w & 1) << 6;
  f32x4 acc[4][4];
  #pragma unroll
  for (int mi = 0; mi < 4; ++mi)
    #pragma unroll
    for (int ni = 0; ni < 4; ++ni)
      acc[mi][ni] = (f32x4){0.f, 0.f, 0.f, 0.f};

  for (int k0 = 0; k0 < K; k0 += 64) {
    #pragma unroll
    for (int r2 = 0; r2 < 4; ++r2) {
      int linear = (r2 << 8) + tid;
      int row = linear >> 3;
      int ch = linear & 7;
      gld_lds16(A  + (size_t)(m0 + row) * K + k0 + ch * 8, As + linear * 8);
      gld_lds16(Bw + (size_t)(n0 + row) * K + k0 + ch * 8, Bs + linear * 8);
    }
    __syncthreads();
    #pragma unroll
    for (int kk = 0; kk < 64; kk += 32) {
      bf16x8_t af[4], bq[4];
      int lr = lane & 15;
      int lk = ((lane >> 4) << 3) + kk;
      #pragma unroll
      for (int mi = 0; mi < 4; ++mi)
        af[mi] = *(const bf16x8_t*)(As + ((wm + (mi << 4) + lr) << 6) + lk);
      #pragma unroll
      for (int ni = 0; ni < 4; ++ni)
        bq[ni] = *(const bf16x8_t*)(Bs + ((wn + (ni << 4) + lr) << 6) + lk);
      #pragma unroll
      for (int mi = 0; mi < 4; ++mi)
        #pragma unroll
        for (int ni = 0; ni < 4; ++ni)
          acc[mi][ni] = __builtin_amdgcn_mfma_f32_16x16x32_bf16(af[mi], bq[ni], acc[mi][ni], 0, 0, 0);
    }
    __syncthreads();
  }

  // stage transposed: stg[col_local][row_local]
  int lr = lane & 15, lg = lane >> 4;
  #pragma unroll
  for (int mi = 0; mi < 4; ++mi)
    #pragma unroll
    for (int ni = 0; ni < 4; ++ni) {
      int cl = wn + (ni << 4) + lr;
      int rl = wm + (mi << 4) + (lg << 2);
      f32x4 a = acc[mi][ni];
      #pragma unroll
      for (int i = 0; i < 4; ++i)
        smem[cl * 128 + rl + i] = f2bf(a[i]);
    }
  __syncthreads();

  int cl = tid >> 1;
  int half = tid & 1;
  int b = m0 >> 14;
  int pix = (m0 & 16383) + half * 64;
  int c = n0 + cl;
  const unsigned short* srow = smem + cl * 128 + half * 64;
  unsigned short* orow = outp + ((size_t)b * 256 + c) * 16384 + pix;
  #pragma unroll
  for (int jj = 0; jj < 8; ++jj)
    *(bf16x8_t*)(orow + jj * 8) = *(const bf16x8_t*)(srow + jj * 8);
}

// ---------------- WO fused: x1_nchw_bf16 = xbf + o@wo^T + wo_b  (K=256, N=256) ----------------
__global__ __launch_bounds__(256) void gemm_wof_kernel(const unsigned short* __restrict__ A,
    const unsigned short* __restrict__ Bw, const float* __restrict__ bias,
    const unsigned short* __restrict__ xbf, unsigned short* __restrict__ outp) {
  __shared__ unsigned short smem[16384];
  unsigned short* As = smem;
  unsigned short* Bs = smem + 8192;
  const int K = 256;
  int tid = threadIdx.x;
  int m0 = blockIdx.x << 7;
  int n0 = blockIdx.y << 7;
  int w = tid >> 6, lane = tid & 63;
  int wm = (w >> 1) << 6, wn = (w & 1) << 6;
  f32x4 acc[4][4];
  #pragma unroll
  for (int mi = 0; mi < 4; ++mi)
    #pragma unroll
    for (int ni = 0; ni < 4; ++ni)
      acc[mi][ni] = (f32x4){0.f, 0.f, 0.f, 0.f};

  for (int k0 = 0; k0 < K; k0 += 64) {
    #pragma unroll
    for (int r2 = 0; r2 < 4; ++r2) {
      int linear = (r2 << 8) + tid;
      int row = linear >> 3;
      int ch = linear & 7;
      gld_lds16(A  + (size_t)(m0 + row) * K + k0 + ch * 8, As + linear * 8);
      gld_lds16(Bw + (size_t)(n0 + row) * K + k0 + ch * 8, Bs + linear * 8);
    }
    __syncthreads();
    #pragma unroll
    for (int kk = 0; kk < 64; kk += 32) {
      bf16x8_t af[4], bq[4];
      int lr = lane & 15;
      int lk = ((lane >> 4) << 3) + kk;
      #pragma unroll
      for (int mi = 0; mi < 4; ++mi)
        af[mi] = *(const bf16x8_t*)(As + ((wm + (mi << 4) + lr) << 6) + lk);
      #pragma unroll
      for (int ni = 0; ni < 4; ++ni)
        bq[ni] = *(const bf16x8_t*)(Bs + ((wn + (ni << 4) + lr) << 6) + lk);
      #pragma unroll
      for (int mi = 0; mi < 4; ++mi)
        #pragma unroll
        for (int ni = 0; ni < 4; ++ni)
          acc[mi][ni] = __builtin_amdgcn_mfma_f32_16x16x32_bf16(af[mi], bq[ni], acc[mi][ni], 0, 0, 0);
    }
    __syncthreads();
  }

  // stage transposed: stg[col_local][row_local]
  int lr = lane & 15, lg = lane >> 4;
  #pragma unroll
  for (int mi = 0; mi < 4; ++mi)
    #pragma unroll
    for (int ni = 0; ni < 4; ++ni) {
      int cl = wn + (ni << 4) + lr;
      int rl = wm + (mi << 4) + (lg << 2);
      f32x4 a = acc[mi][ni];
      #pragma unroll
      for (int i = 0; i < 4; ++i)
        smem[cl * 128 + rl + i] = f2bf(a[i]);
    }
  __syncthreads();

  int cl = tid >> 1;
  int half = tid & 1;
  int b = m0 >> 14;
  int pix = (m0 & 16383) + half * 64;
  int c = n0 + cl;
  const unsigned short* srow = smem + cl * 128 + half * 64;
  size_t gbase = ((size_t)b * 256 + c) * 16384 + pix;
  const unsigned short* xrow = xbf + gbase;
  unsigned short* orow = outp + gbase;
  float bb = bias[c];
  #pragma unroll
  for (int jj = 0; jj < 8; ++jj) {
    bf16x8_t sv = *(const bf16x8_t*)(srow + jj * 8);
    bf16x8_t xv = *(const bf16x8_t*)(xrow + jj * 8);
    bf16x8_t ov;
    #pragma unroll
    for (int e = 0; e < 8; ++e)
      ov[e] = (short)f2bf(bf2f((unsigned short)sv[e]) + bf2f((unsigned short)xv[e]) + bb);
    *(bf16x8_t*)(orow + jj * 8) = ov;
  }
}

// ---------------- fused MLP: out_nchw = x1 + GELU(z@w1^T + b1)@w2^T + b2 ----------------
// One block = 64 pixels. z [131072][256] bf16 pixel-major; w1 [1024][256]; w2 [256][1024];
// x1 bf16 NCHW; out fp32 NCHW. LDS: ztile (XOR-swizzled chunks) + hbuf (padded 136).
__global__ __launch_bounds__(256, 3) void gemm_mlp_kernel(const unsigned short* __restrict__ z,
    const unsigned short* __restrict__ w1, const float* __restrict__ b1,
    const unsigned short* __restrict__ w2, const float* __restrict__ b2,
    const unsigned short* __restrict__ x1, float* __restrict__ outp) {
  __shared__ unsigned short ztile[64 * 256];   // 32 KB; reused as stg[256][64] in epilogue
  __shared__ unsigned short hbuf[64 * 136];    // 17 KB, padded rows (136) -> conflict-free frags
  int tid = threadIdx.x;
  int m0 = blockIdx.x << 6;                    // 64-pixel tile, always within one image
  int w = tid >> 6, lane = tid & 63;
  int g = lane >> 4, lr = lane & 15;

  // ---- stage z-tile once, XOR-swizzled source (linear LDS dest; read applies same XOR) ----
  #pragma unroll
  for (int r2 = 0; r2 < 8; ++r2) {
    int linear = (r2 << 8) + tid;              // 0..2047 chunks of 16B
    int row = linear >> 5;                     // 32 chunks per 256-el row
    int ch = linear & 31;
    gld_lds16(z + (size_t)(m0 + row) * 256 + ((ch ^ (row & 7)) << 3), ztile + linear * 8);
  }
  __syncthreads();

  f32x4 acc[4][4];                             // out[64][w*64..w*64+64)
  #pragma unroll
  for (int mi = 0; mi < 4; ++mi)
    #pragma unroll
    for (int ni = 0; ni < 4; ++ni)
      acc[mi][ni] = (f32x4){0.f, 0.f, 0.f, 0.f};

  #pragma unroll 1
  for (int j = 0; j < 8; ++j) {
    // ---- h_j[64][128] = z @ w1_j^T; wave w computes cols [w*32, w*32+32) ----
    f32x4 hacc[4][2];
    #pragma unroll
    for (int mi = 0; mi < 4; ++mi) {
      hacc[mi][0] = (f32x4){0.f, 0.f, 0.f, 0.f};
      hacc[mi][1] = (f32x4){0.f, 0.f, 0.f, 0.f};
    }
    #pragma unroll
    for (int k32 = 0; k32 < 8; ++k32) {
      bf16x8_t af[4], bq[2];
      int cidx = (k32 << 2) + g;               // 16B-chunk index within the row
      #pragma unroll
      for (int mi = 0; mi < 4; ++mi) {
        int row = mi * 16 + lr;
        af[mi] = *(const bf16x8_t*)(ztile + row * 256 + ((cidx ^ (row & 7)) << 3));
      }
      int kb = (k32 << 5) + (g << 3);
      #pragma unroll
      for (int ni = 0; ni < 2; ++ni)
        bq[ni] = *(const bf16x8_t*)(w1 + (size_t)(j * 128 + w * 32 + ni * 16 + lr) * 256 + kb);
      #pragma unroll
      for (int mi = 0; mi < 4; ++mi)
        #pragma unroll
        for (int ni = 0; ni < 2; ++ni)
          hacc[mi][ni] = __builtin_amdgcn_mfma_f32_16x16x32_bf16(af[mi], bq[ni], hacc[mi][ni], 0, 0, 0);
    }
    // ---- bias + exact GELU -> hbuf (bf16) ----
    #pragma unroll
    for (int ni = 0; ni < 2; ++ni) {
      int hcol = w * 32 + ni * 16 + lr;        // 0..127
      float bb = b1[j * 128 + hcol];
      #pragma unroll
      for (int mi = 0; mi < 4; ++mi) {
        #pragma unroll
        for (int i = 0; i < 4; ++i) {
          float v = hacc[mi][ni][i] + bb;
          v = 0.5f * v * (1.0f + erff(v * 0.70710678118654752f));
          hbuf[(mi * 16 + g * 4 + i) * 136 + hcol] = f2bf(v);
        }
      }
    }
    __syncthreads();
    // ---- out += h_j @ w2_j^T; wave w computes out cols [w*64, w*64+64) ----
    #pragma unroll
    for (int ks = 0; ks < 4; ++ks) {
      int kb = (ks << 5) + (g << 3);
      bf16x8_t pf[4], bq2[4];
      #pragma unroll
      for (int mi = 0; mi < 4; ++mi)
        pf[mi] = *(const bf16x8_t*)(hbuf + (mi * 16 + lr) * 136 + kb);
      #pragma unroll
      for (int ni = 0; ni < 4; ++ni)
        bq2[ni] = *(const bf16x8_t*)(w2 + (size_t)(w * 64 + ni * 16 + lr) * 1024 + j * 128 + kb);
      #pragma unroll
      for (int mi = 0; mi < 4; ++mi)
        #pragma unroll
        for (int ni = 0; ni < 4; ++ni)
          acc[mi][ni] = __builtin_amdgcn_mfma_f32_16x16x32_bf16(pf[mi], bq2[ni], acc[mi][ni], 0, 0, 0);
    }
    __syncthreads();                            // hbuf reused next j (and ztile read done at j=7)
  }

  // ---- epilogue: stg[col][row] bf16 (XOR-swizzled rows, aliases ztile), then NCHW + x1 + b2 ----
  unsigned short* stg = ztile;
  #pragma unroll
  for (int mi = 0; mi < 4; ++mi)
    #pragma unroll
    for (int ni = 0; ni < 4; ++ni) {
      int cl = w * 64 + ni * 16 + lr;
      int rl = mi * 16 + g * 4;
      f32x4 a = acc[mi][ni];
      #pragma unroll
      for (int i = 0; i < 4; ++i)
        stg[cl * 64 + ((rl + i) ^ ((cl & 7) << 3))] = f2bf(a[i]);
    }
  __syncthreads();
  int c = tid;                                 // output channel 0..255
  int b = m0 >> 14;
  int pix = m0 & 16383;
  size_t gbase = ((size_t)b * 256 + c) * 16384 + pix;
  const unsigned short* xrow = x1 + gbase;
  float* orow = outp + gbase;
  float bb = b2[c];
  #pragma unroll
  for (int jj = 0; jj < 8; ++jj) {
    bf16x8_t sv = *(const bf16x8_t*)(stg + c * 64 + ((jj ^ (c & 7)) << 3));  // rows jj*8..+8
    bf16x8_t xv = *(const bf16x8_t*)(xrow + jj * 8);
    #pragma unroll
    for (int e = 0; e < 8; ++e)
      orow[jj * 8 + e] = bf2f((unsigned short)sv[e]) + bf2f((unsigned short)xv[e]) + bb;
  }
}

// ---------------- MFMA windowed attention: one window per block, 4 waves, 2 heads/wave ----------------
// qt-sliced: per 16-row q-slice do S -> softmax -> PV, so the P LDS bounce is only [16][72]/wave.
__global__ __launch_bounds__(256, 4) void attn_kernel(const unsigned short* __restrict__ qg,
    const unsigned short* __restrict__ kg, const unsigned short* __restrict__ vt,
    const float* __restrict__ rpb, unsigned short* __restrict__ og) {
  __shared__ float rpbf[1800];
  __shared__ unsigned short pbuf[4][16 * 72];
  // XCD-bijective swizzle: 2048 blocks, 8 XCDs -> each image (256 windows) on one XCD.
  int wi = (blockIdx.x & 7) * 256 + (blockIdx.x >> 3);
  int b = wi >> 8, wh = (wi >> 4) & 15, ww = wi & 15;
  int tid = threadIdx.x;
  int w = tid >> 6, lane = tid & 63;
  int g = lane >> 4, lr = lane & 15;
  for (int idx = tid; idx < 1800; idx += 256) rpbf[idx] = rpb[idx];
  __syncthreads();

  int rowpix = (wh * 8) * 128 + ww * 8;
  size_t ibase = ((size_t)b << 14) + rowpix;
  unsigned short* pb = pbuf[w];
  const float scale = 0.17677669529663689f;

  #pragma unroll 1
  for (int hh = 0; hh < 2; ++hh) {
    int h = w * 2 + hh;
    bf16x8_t qf[4], kf[4];
    #pragma unroll
    for (int t = 0; t < 4; ++t) {
      size_t tok = ibase + (size_t)(t * 2 + (lr >> 3)) * 128 + (lr & 7);
      qf[t] = *(const bf16x8_t*)(qg + tok * 256 + h * 32 + g * 8);
      kf[t] = *(const bf16x8_t*)(kg + tok * 256 + h * 32 + g * 8);
    }
    bf16x8_t vfr[2][2];
    #pragma unroll
    for (int ks = 0; ks < 2; ++ks)
      #pragma unroll
      for (int dt = 0; dt < 2; ++dt) {
        size_t plane = (size_t)b * 256 + h * 32 + dt * 16 + lr;
        vfr[ks][dt] = *(const bf16x8_t*)(vt + (plane << 14) + rowpix + (size_t)(ks * 4 + g) * 128);
      }
    const float* rb = &rpbf[h * 225];

    #pragma unroll 1
    for (int qt = 0; qt < 4; ++qt) {
      f32x4 sacc[4];
      #pragma unroll
      for (int kt = 0; kt < 4; ++kt)
        sacc[kt] = __builtin_amdgcn_mfma_f32_16x16x32_bf16(qf[qt], kf[kt],
                     (f32x4){0.f, 0.f, 0.f, 0.f}, 0, 0, 0);
      float sums[4];
      #pragma unroll
      for (int i = 0; i < 4; ++i) {
        int q = qt * 16 + g * 4 + i;
        int il = q >> 3, jl = q & 7;
        float v[4];
        #pragma unroll
        for (int kt = 0; kt < 4; ++kt) {
          int kv = kt * 16 + lr;
          v[kt] = sacc[kt][i] * scale + rb[(il - (kv >> 3) + 7) * 15 + (jl - (kv & 7) + 7)];
        }
        float mx = fmaxf(fmaxf(v[0], v[1]), fmaxf(v[2], v[3]));
        mx = fmaxf(mx, __shfl_xor(mx, 1));
        mx = fmaxf(mx, __shfl_xor(mx, 2));
        mx = fmaxf(mx, __shfl_xor(mx, 4));
        mx = fmaxf(mx, __shfl_xor(mx, 8));
        float sm = 0.f;
        #pragma unroll
        for (int kt = 0; kt < 4; ++kt) { v[kt] = __expf(v[kt] - mx); sm += v[kt]; }
        sm += __shfl_xor(sm, 1);
        sm += __shfl_xor(sm, 2);
        sm += __shfl_xor(sm, 4);
        sm += __shfl_xor(sm, 8);
        sums[i] = sm;
        #pragma unroll
        for (int kt = 0; kt < 4; ++kt)
          pb[(g * 4 + i) * 72 + kt * 16 + lr] = f2bf(v[kt]);
      }
      f32x4 oacc[2] = {(f32x4){0.f, 0.f, 0.f, 0.f}, (f32x4){0.f, 0.f, 0.f, 0.f}};
      #pragma unroll
      for (int ks = 0; ks < 2; ++ks) {
        bf16x8_t pf = *(const bf16x8_t*)(pb + lr * 72 + ks * 32 + g * 8);
        oacc[0] = __builtin_amdgcn_mfma_f32_16x16x32_bf16(pf, vfr[ks][0], oacc[0], 0, 0, 0);
        oacc[1] = __builtin_amdgcn_mfma_f32_16x16x32_bf16(pf, vfr[ks][1], oacc[1], 0, 0, 0);
      }
      #pragma unroll
      for (int i = 0; i < 4; ++i) {
        int q = qt * 16 + g * 4 + i;
        float inv = 1.0f / sums[i];
        size_t tok = ibase + (size_t)(q >> 3) * 128 + (q & 7);
        og[tok * 256 + h * 32 + lr] = f2bf(oacc[0][i] * inv);
        og[tok * 256 + h * 32 + 16 + lr] = f2bf(oacc[1][i] * inv);
      }
    }
  }
}

// ---------------- depthwise 7x7 conv (bf16 in/out, fp32 math), pad 3, + bias ----------------
__global__ __launch_bounds__(256) void dwconv_kernel(const unsigned short* __restrict__ x1,
    const float* __restrict__ w, const float* __restrict__ bias, unsigned short* __restrict__ outp) {
  int bc = blockIdx.y;                  // 0..2047 (b*256 + c)
  int c = bc & 255;
  int y0 = blockIdx.x << 6;             // 0 or 64
  __shared__ unsigned short tile[70 * 144];
  __shared__ float wf[49];
  const unsigned short* plane = x1 + ((size_t)bc << 14);
  int tid = threadIdx.x;

  for (int idx = tid; idx < 70 * 16; idx += 256) {
    int row = idx >> 4, ch = idx & 15;
    int gy = y0 - 3 + row;
    bf16x8_t v = (bf16x8_t){0, 0, 0, 0, 0, 0, 0, 0};
    if (gy >= 0 && gy < 128) v = *(const bf16x8_t*)(plane + gy * 128 + ch * 8);
    *(bf16x8_t*)(&tile[row * 144 + 8 + ch * 8]) = v;
  }
  for (int idx = tid; idx < 70 * 6; idx += 256) {
    int row = idx / 6, e = idx % 6;
    int col = (e < 3) ? (5 + e) : (133 + e);
    tile[row * 144 + col] = 0;
  }
  if (tid < 49) wf[tid] = w[c * 49 + tid];
  __syncthreads();

  int r = tid >> 2;
  int c0 = (tid & 3) << 5;
  float acc[32];
  float bb = bias[c];
  #pragma unroll
  for (int i = 0; i < 32; ++i) acc[i] = bb;

  #pragma unroll
  for (int u = 0; u < 7; ++u) {
    const unsigned short* rowp = &tile[(r + u) * 144 + c0];
    float f[48];
    #pragma unroll
    for (int k = 0; k < 6; ++k) {
      bf16x8_t v = *(const bf16x8_t*)(rowp + k * 8);
      #pragma unroll
      for (int e = 0; e < 8; ++e) f[k * 8 + e] = bf2f((unsigned short)v[e]);
    }
    #pragma unroll
    for (int t = 0; t < 7; ++t) {
      float wv = wf[u * 7 + t];
      #pragma unroll
      for (int i = 0; i < 32; ++i) acc[i] += f[i + 5 + t] * wv;
    }
  }

  unsigned short* orow = outp + ((size_t)bc << 14) + (size_t)(y0 + r) * 128 + c0;
  #pragma unroll
  for (int k = 0; k < 4; ++k) {
    bf16x8_t v;
    #pragma unroll
    for (int e = 0; e < 8; ++e) v[e] = (short)f2bf(acc[k * 8 + e]);
    *(bf16x8_t*)(orow + k * 8) = v;
  }
}

extern "C" void kernel_launch(void* const* d_in, const int* in_sizes, int n_in,
                              void* d_out, int out_size, void* d_ws, size_t ws_size,
                              hipStream_t stream) {
  const float* x    = (const float*)d_in[0];
  const float* t    = (const float*)d_in[1];
  const float* an_g = (const float*)d_in[2];
  const float* an_b = (const float*)d_in[3];
  const float* wq   = (const float*)d_in[4];
  const float* wk   = (const float*)d_in[5];
  const float* wv   = (const float*)d_in[6];
  const float* wo_w = (const float*)d_in[7];
  const float* wo_b = (const float*)d_in[8];
  const float* rpb  = (const float*)d_in[9];
  const float* dw_w = (const float*)d_in[10];
  const float* dw_b = (const float*)d_in[11];
  const float* fn_g = (const float*)d_in[12];
  const float* fn_b = (const float*)d_in[13];
  const float* w1   = (const float*)d_in[14];
  const float* b1   = (const float*)d_in[15];
  const float* w2   = (const float*)d_in[16];
  const float* b2   = (const float*)d_in[17];
  float* outp = (float*)d_out;

  char* ws = (char*)d_ws;
  const size_t MB = 1024ull * 1024ull;
  float* gvec = (float*)ws;                                   // 32 KB
  unsigned short* wbf = (unsigned short*)(ws + 32768);        // 1.5 MiB
  unsigned short* P = (unsigned short*)(ws + 2 * MB);         // 64 MiB: y -> o -> z
  unsigned short* Q = (unsigned short*)(ws + 66 * MB);        // 64 MiB: q -> y2
  unsigned short* R = (unsigned short*)(ws + 130 * MB);       // 64 MiB: k -> x1 (persists)
  // d_out (128 MiB) scratch regions, both dead before gemm_mlp rewrites d_out:
  unsigned short* xbf  = (unsigned short*)d_out;                      // [0,64) MiB bf16 copy of x
  unsigned short* vbuf = (unsigned short*)((char*)d_out + 64 * MB);   // [64,128) MiB v NCHW bf16

  unsigned short* wq_bf = wbf;
  unsigned short* wk_bf = wbf + 65536;
  unsigned short* wv_bf = wbf + 131072;
  unsigned short* wo_bf = wbf + 196608;
  unsigned short* w1_bf = wbf + 262144;
  unsigned short* w2_bf = wbf + 524288;

  tvec_kernel<<<dim3(8, 4), 256, 0, stream>>>(t, an_g, an_b, fn_g, fn_b, gvec);
  wconv_kernel<<<3072, 256, 0, stream>>>(wq, wk, wv, wo_w, w1, w2, wbf);

  // y = rms_film(x) -> P ; also xbf = bf16(x) NCHW
  film_kernel<0, 1><<<2048, 256, 0, stream>>>(x, gvec, 0, P, xbf);

  // q,k pixel-major; v NCHW bf16 (separate GEMMs — fused variant regressed, round 7)
  gemm_kernel<0><<<dim3(1024, 2), 256, 0, stream>>>(P, wq_bf, nullptr, Q, 256, 256);
  gemm_kernel<0><<<dim3(1024, 2), 256, 0, stream>>>(P, wk_bf, nullptr, R, 256, 256);
  gemm_t_kernel<<<dim3(1024, 2), 256, 0, stream>>>(P, wv_bf, vbuf);

  // windowed attention (MFMA) -> o (P; y dead)
  attn_kernel<<<2048, 256, 0, stream>>>(Q, R, vbuf, rpb, P);

  // WO fused: x1 = bf16(xbf + o@wo^T + wo_b) NCHW -> R (k dead)
  gemm_wof_kernel<<<dim3(1024, 2), 256, 0, stream>>>(P, wo_bf, wo_b, xbf, R);

  // convnext: dwconv (x1 -> y2 in Q) -> film2 (-> z in P)
  dwconv_kernel<<<dim3(2, 2048), 256, 0, stream>>>(R, dw_w, dw_b, Q);
  film_kernel<1, 0><<<2048, 256, 0, stream>>>(Q, gvec, 1, P, nullptr);

  // fused MLP (MLP1 + GELU + MLP2 + residual) -> d_out, no hmid round-trip
  gemm_mlp_kernel<<<2048, 256, 0, stream>>>(P, w1_bf, b1, w2_bf, b2, R, outp);
}

// Round 9
// 838.142 us; speedup vs baseline: 1.1751x; 1.0641x over previous
//
#include <hip/hip_runtime.h>
#include <math.h>

typedef __attribute__((ext_vector_type(8))) short bf16x8_t;
typedef __attribute__((ext_vector_type(4))) float f32x4;

__device__ __forceinline__ unsigned short f2bf(float f) {
  unsigned int u = __builtin_bit_cast(unsigned int, f);
  u += 0x7FFFu + ((u >> 16) & 1u);
  return (unsigned short)(u >> 16);
}
__device__ __forceinline__ float bf2f(unsigned short h) {
  unsigned int u = ((unsigned int)h) << 16;
  return __builtin_bit_cast(float, u);
}

typedef const __attribute__((address_space(1))) void* as1cv;
typedef __attribute__((address_space(3))) void* as3v;

__device__ __forceinline__ void gld_lds16(const unsigned short* g, unsigned short* l) {
  __builtin_amdgcn_global_load_lds((as1cv)g, (as3v)l, 16, 0, 0);
}

// ---------------- t-vector projections: gvec[4][8][256] = {an_g, an_b, fn_g, fn_b} ----------------
__global__ __launch_bounds__(256) void tvec_kernel(const float* __restrict__ t,
    const float* __restrict__ an_g, const float* __restrict__ an_b,
    const float* __restrict__ fn_g, const float* __restrict__ fn_b,
    float* __restrict__ gvec) {
  int d = threadIdx.x;
  int b = blockIdx.x;      // 0..7
  int m = blockIdx.y;      // 0..3
  __shared__ float ts[256];
  ts[d] = t[b * 256 + d];
  __syncthreads();
  const float* W = (m == 0) ? an_g : (m == 1) ? an_b : (m == 2) ? fn_g : fn_b;
  float acc = 0.f;
  #pragma unroll 8
  for (int k = 0; k < 256; ++k) acc += ts[k] * W[d * 256 + k];
  gvec[(m * 8 + b) * 256 + d] = acc;
}

// ---------------- weights fp32 -> bf16 (concat: wq,wk,wv,wo,w1,w2) ----------------
__global__ __launch_bounds__(256) void wconv_kernel(const float* __restrict__ wq,
    const float* __restrict__ wk, const float* __restrict__ wv, const float* __restrict__ wo,
    const float* __restrict__ w1, const float* __restrict__ w2,
    unsigned short* __restrict__ outp) {
  int i = blockIdx.x * 256 + threadIdx.x;   // total 786432
  const float* src; int off;
  if      (i <  65536) { src = wq; off = 0; }
  else if (i < 131072) { src = wk; off = 65536; }
  else if (i < 196608) { src = wv; off = 131072; }
  else if (i < 262144) { src = wo; off = 196608; }
  else if (i < 524288) { src = w1; off = 262144; }
  else                 { src = w2; off = 524288; }
  outp[i] = f2bf(src[i - off]);
}

// ---------------- RMS-FiLM: NCHW (fp32 or bf16) -> [131072][256] bf16 (pixel-major) ----------------
// WX: also write a bf16 NCHW copy of the raw input (xbf).
template<int IS_BF, int WX>
__global__ __launch_bounds__(256) void film_kernel(const void* __restrict__ in_,
    const float* __restrict__ gvec, int gsel, unsigned short* __restrict__ outbf,
    unsigned short* __restrict__ xbf) {
  const float* inf = (const float*)in_;
  const unsigned short* inb = (const unsigned short*)in_;
  int blk = blockIdx.x;             // 2048 blocks, 64 pixels each
  int b = blk >> 8;
  int p0 = (blk & 255) << 6;
  int lane = threadIdx.x & 63;      // pixel within group (phase A)
  int cg = threadIdx.x >> 6;        // channel group 0..3
  __shared__ unsigned short vals[64][264];
  __shared__ float ssred[4][64];
  __shared__ float rinvs[64];
  size_t base = ((size_t)b << 22) + p0;
  float ss = 0.f;
  #pragma unroll 4
  for (int ci = 0; ci < 64; ++ci) {
    int c = (cg << 6) + ci;
    size_t idx = base + ((size_t)c << 14) + lane;
    float v = IS_BF ? bf2f(inb[idx]) : inf[idx];
    ss += v * v;
    unsigned short hv = f2bf(v);
    vals[lane][c] = hv;
    if (WX) xbf[idx] = hv;
  }
  ssred[cg][lane] = ss;
  __syncthreads();
  if (threadIdx.x < 64) {
    float s = ssred[0][threadIdx.x] + ssred[1][threadIdx.x] + ssred[2][threadIdx.x] + ssred[3][threadIdx.x];
    rinvs[threadIdx.x] = rsqrtf(s * (1.0f / 256.0f) + 1e-6f);
  }
  __syncthreads();
  int pix = threadIdx.x >> 2;
  int c0 = (threadIdx.x & 3) << 6;
  float rv = rinvs[pix];
  const float* gp = gvec + ((gsel * 2 + 0) * 8 + b) * 256;
  const float* bp = gvec + ((gsel * 2 + 1) * 8 + b) * 256;
  unsigned short* orow = outbf + (((size_t)b << 14) + p0 + pix) * 256 + c0;
  #pragma unroll
  for (int ch = 0; ch < 8; ++ch) {
    bf16x8_t pack;
    #pragma unroll
    for (int e = 0; e < 8; ++e) {
      int c = c0 + ch * 8 + e;
      float v = bf2f(vals[pix][c]);
      float o = gp[c] * v * rv + bp[c];
      pack[e] = (short)f2bf(o);
    }
    *(bf16x8_t*)(orow + ch * 8) = pack;
  }
}

// ---------------- bf16 GEMM: out[M][N] = A[M][K] @ Bw[N][K]^T ----------------
template<int DO_GELU>
__global__ __launch_bounds__(256) void gemm_kernel(const unsigned short* __restrict__ A,
    const unsigned short* __restrict__ Bw, const float* __restrict__ bias,
    unsigned short* __restrict__ outp, int K, int N) {
  __shared__ unsigned short As[128 * 64];
  __shared__ unsigned short Bs[128 * 64];
  int tid = threadIdx.x;
  int m0 = blockIdx.x << 7;
  int n0 = blockIdx.y << 7;
  int w = tid >> 6, lane = tid & 63;
  int wm = (w >> 1) << 6, wn = (w & 1) << 6;
  f32x4 acc[4][4];
  #pragma unroll
  for (int mi = 0; mi < 4; ++mi)
    #pragma unroll
    for (int ni = 0; ni < 4; ++ni)
      acc[mi][ni] = (f32x4){0.f, 0.f, 0.f, 0.f};

  for (int k0 = 0; k0 < K; k0 += 64) {
    #pragma unroll
    for (int r2 = 0; r2 < 4; ++r2) {
      int linear = (r2 << 8) + tid;       // 0..1023 (16B chunks)
      int row = linear >> 3;
      int ch = linear & 7;
      gld_lds16(A  + (size_t)(m0 + row) * K + k0 + ch * 8, As + linear * 8);
      gld_lds16(Bw + (size_t)(n0 + row) * K + k0 + ch * 8, Bs + linear * 8);
    }
    __syncthreads();
    #pragma unroll
    for (int kk = 0; kk < 64; kk += 32) {
      bf16x8_t af[4], bq[4];
      int lr = lane & 15;
      int lk = ((lane >> 4) << 3) + kk;
      #pragma unroll
      for (int mi = 0; mi < 4; ++mi)
        af[mi] = *(const bf16x8_t*)(As + ((wm + (mi << 4) + lr) << 6) + lk);
      #pragma unroll
      for (int ni = 0; ni < 4; ++ni)
        bq[ni] = *(const bf16x8_t*)(Bs + ((wn + (ni << 4) + lr) << 6) + lk);
      #pragma unroll
      for (int mi = 0; mi < 4; ++mi)
        #pragma unroll
        for (int ni = 0; ni < 4; ++ni)
          acc[mi][ni] = __builtin_amdgcn_mfma_f32_16x16x32_bf16(af[mi], bq[ni], acc[mi][ni], 0, 0, 0);
    }
    __syncthreads();
  }
  int lr = lane & 15, lg = lane >> 4;
  #pragma unroll
  for (int mi = 0; mi < 4; ++mi) {
    #pragma unroll
    for (int ni = 0; ni < 4; ++ni) {
      int col = n0 + wn + (ni << 4) + lr;
      int row = m0 + wm + (mi << 4) + (lg << 2);
      f32x4 a = acc[mi][ni];
      #pragma unroll
      for (int i = 0; i < 4; ++i) {
        float v = a[i];
        if (DO_GELU) {
          v += bias[col];
          v = 0.5f * v * (1.0f + erff(v * 0.70710678118654752f));
        }
        outp[(size_t)(row + i) * N + col] = f2bf(v);
      }
    }
  }
}

// ---------------- V projection with NCHW bf16 output: vt[(b*256+col)*16384 + pix] ----------------
__global__ __launch_bounds__(256) void gemm_t_kernel(const unsigned short* __restrict__ A,
    const unsigned short* __restrict__ Bw, unsigned short* __restrict__ outp) {
  __shared__ unsigned short smem[16384];   // As(16K) | Bs(16K), reused as stg[128][128]
  unsigned short* As = smem;
  unsigned short* Bs = smem + 8192;
  const int K = 256;
  int tid = threadIdx.x;
  int m0 = blockIdx.x << 7;
  int n0 = blockIdx.y << 7;
  int w = tid >> 6, lane = tid & 63;
  int wm = (w >> 1) << 6, wn = (w & 1) << 6;
  f32x4 acc[4][4];
  #pragma unroll
  for (int mi = 0; mi < 4; ++mi)
    #pragma unroll
    for (int ni = 0; ni < 4; ++ni)
      acc[mi][ni] = (f32x4){0.f, 0.f, 0.f, 0.f};

  for (int k0 = 0; k0 < K; k0 += 64) {
    #pragma unroll
    for (int r2 = 0; r2 < 4; ++r2) {
      int linear = (r2 << 8) + tid;
      int row = linear >> 3;
      int ch = linear & 7;
      gld_lds16(A  + (size_t)(m0 + row) * K + k0 + ch * 8, As + linear * 8);
      gld_lds16(Bw + (size_t)(n0 + row) * K + k0 + ch * 8, Bs + linear * 8);
    }
    __syncthreads();
    #pragma unroll
    for (int kk = 0; kk < 64; kk += 32) {
      bf16x8_t af[4], bq[4];
      int lr = lane & 15;
      int lk = ((lane >> 4) << 3) + kk;
      #pragma unroll
      for (int mi = 0; mi < 4; ++mi)
        af[mi] = *(const bf16x8_t*)(As + ((wm + (mi << 4) + lr) << 6) + lk);
      #pragma unroll
      for (int ni = 0; ni < 4; ++ni)
        bq[ni] = *(const bf16x8_t*)(Bs + ((wn + (ni << 4) + lr) << 6) + lk);
      #pragma unroll
      for (int mi = 0; mi < 4; ++mi)
        #pragma unroll
        for (int ni = 0; ni < 4; ++ni)
          acc[mi][ni] = __builtin_amdgcn_mfma_f32_16x16x32_bf16(af[mi], bq[ni], acc[mi][ni], 0, 0, 0);
    }
    __syncthreads();
  }

  // stage transposed: stg[col_local][row_local]
  int lr = lane & 15, lg = lane >> 4;
  #pragma unroll
  for (int mi = 0; mi < 4; ++mi)
    #pragma unroll
    for (int ni = 0; ni < 4; ++ni) {
      int cl = wn + (ni << 4) + lr;
      int rl = wm + (mi << 4) + (lg << 2);
      f32x4 a = acc[mi][ni];
      #pragma unroll
      for (int i = 0; i < 4; ++i)
        smem[cl * 128 + rl + i] = f2bf(a[i]);
    }
  __syncthreads();

  int cl = tid >> 1;
  int half = tid & 1;
  int b = m0 >> 14;
  int pix = (m0 & 16383) + half * 64;
  int c = n0 + cl;
  const unsigned short* srow = smem + cl * 128 + half * 64;
  unsigned short* orow = outp + ((size_t)b * 256 + c) * 16384 + pix;
  #pragma unroll
  for (int jj = 0; jj < 8; ++jj)
    *(bf16x8_t*)(orow + jj * 8) = *(const bf16x8_t*)(srow + jj * 8);
}

// ---------------- WO fused: x1_nchw_bf16 = xbf + o@wo^T + wo_b  (K=256, N=256) ----------------
__global__ __launch_bounds__(256) void gemm_wof_kernel(const unsigned short* __restrict__ A,
    const unsigned short* __restrict__ Bw, const float* __restrict__ bias,
    const unsigned short* __restrict__ xbf, unsigned short* __restrict__ outp) {
  __shared__ unsigned short smem[16384];
  unsigned short* As = smem;
  unsigned short* Bs = smem + 8192;
  const int K = 256;
  int tid = threadIdx.x;
  int m0 = blockIdx.x << 7;
  int n0 = blockIdx.y << 7;
  int w = tid >> 6, lane = tid & 63;
  int wm = (w >> 1) << 6, wn = (w & 1) << 6;
  f32x4 acc[4][4];
  #pragma unroll
  for (int mi = 0; mi < 4; ++mi)
    #pragma unroll
    for (int ni = 0; ni < 4; ++ni)
      acc[mi][ni] = (f32x4){0.f, 0.f, 0.f, 0.f};

  for (int k0 = 0; k0 < K; k0 += 64) {
    #pragma unroll
    for (int r2 = 0; r2 < 4; ++r2) {
      int linear = (r2 << 8) + tid;
      int row = linear >> 3;
      int ch = linear & 7;
      gld_lds16(A  + (size_t)(m0 + row) * K + k0 + ch * 8, As + linear * 8);
      gld_lds16(Bw + (size_t)(n0 + row) * K + k0 + ch * 8, Bs + linear * 8);
    }
    __syncthreads();
    #pragma unroll
    for (int kk = 0; kk < 64; kk += 32) {
      bf16x8_t af[4], bq[4];
      int lr = lane & 15;
      int lk = ((lane >> 4) << 3) + kk;
      #pragma unroll
      for (int mi = 0; mi < 4; ++mi)
        af[mi] = *(const bf16x8_t*)(As + ((wm + (mi << 4) + lr) << 6) + lk);
      #pragma unroll
      for (int ni = 0; ni < 4; ++ni)
        bq[ni] = *(const bf16x8_t*)(Bs + ((wn + (ni << 4) + lr) << 6) + lk);
      #pragma unroll
      for (int mi = 0; mi < 4; ++mi)
        #pragma unroll
        for (int ni = 0; ni < 4; ++ni)
          acc[mi][ni] = __builtin_amdgcn_mfma_f32_16x16x32_bf16(af[mi], bq[ni], acc[mi][ni], 0, 0, 0);
    }
    __syncthreads();
  }

  // stage transposed: stg[col_local][row_local]
  int lr = lane & 15, lg = lane >> 4;
  #pragma unroll
  for (int mi = 0; mi < 4; ++mi)
    #pragma unroll
    for (int ni = 0; ni < 4; ++ni) {
      int cl = wn + (ni << 4) + lr;
      int rl = wm + (mi << 4) + (lg << 2);
      f32x4 a = acc[mi][ni];
      #pragma unroll
      for (int i = 0; i < 4; ++i)
        smem[cl * 128 + rl + i] = f2bf(a[i]);
    }
  __syncthreads();

  int cl = tid >> 1;
  int half = tid & 1;
  int b = m0 >> 14;
  int pix = (m0 & 16383) + half * 64;
  int c = n0 + cl;
  const unsigned short* srow = smem + cl * 128 + half * 64;
  size_t gbase = ((size_t)b * 256 + c) * 16384 + pix;
  const unsigned short* xrow = xbf + gbase;
  unsigned short* orow = outp + gbase;
  float bb = bias[c];
  #pragma unroll
  for (int jj = 0; jj < 8; ++jj) {
    bf16x8_t sv = *(const bf16x8_t*)(srow + jj * 8);
    bf16x8_t xv = *(const bf16x8_t*)(xrow + jj * 8);
    bf16x8_t ov;
    #pragma unroll
    for (int e = 0; e < 8; ++e)
      ov[e] = (short)f2bf(bf2f((unsigned short)sv[e]) + bf2f((unsigned short)xv[e]) + bb);
    *(bf16x8_t*)(orow + jj * 8) = ov;
  }
}

// ---------------- fused MLP v2: out_nchw = x1 + GELU(z@w1^T + b1)@w2^T + b2 ----------------
// 512 threads / 8 waves per 64-pixel block. Double-buffered hbuf -> ONE barrier per j.
// Wave w: MLP1 h-cols [w*16,+16); MLP2 out-cols [w*32,+32).
__global__ __launch_bounds__(512, 4) void gemm_mlp_kernel(const unsigned short* __restrict__ z,
    const unsigned short* __restrict__ w1, const float* __restrict__ b1,
    const unsigned short* __restrict__ w2, const float* __restrict__ b2,
    const unsigned short* __restrict__ x1, float* __restrict__ outp) {
  __shared__ unsigned short ztile[64 * 256];     // 32 KB; reused as stg[256][64] in epilogue
  __shared__ unsigned short hbuf[2][64 * 136];   // 2 x 17 KB, double-buffered
  int tid = threadIdx.x;
  int m0 = blockIdx.x << 6;                      // 64-pixel tile
  int w = tid >> 6, lane = tid & 63;
  int g = lane >> 4, lr = lane & 15;

  // ---- stage z-tile once, XOR-swizzled source (linear LDS dest; reads apply same XOR) ----
  #pragma unroll
  for (int r2 = 0; r2 < 4; ++r2) {
    int linear = (r2 << 9) + tid;                // 0..2047 chunks of 16B
    int row = linear >> 5;
    int ch = linear & 31;
    gld_lds16(z + (size_t)(m0 + row) * 256 + ((ch ^ (row & 7)) << 3), ztile + linear * 8);
  }
  __syncthreads();

  f32x4 acc[4][2];                               // out rows mi*16.., cols w*32 + ni*16 + lr
  #pragma unroll
  for (int mi = 0; mi < 4; ++mi) {
    acc[mi][0] = (f32x4){0.f, 0.f, 0.f, 0.f};
    acc[mi][1] = (f32x4){0.f, 0.f, 0.f, 0.f};
  }

  #pragma unroll 1
  for (int j = 0; j < 8; ++j) {
    // ---- MLP1: h cols [w*16,+16) for all 64 pixels ----
    f32x4 hacc[4];
    #pragma unroll
    for (int mi = 0; mi < 4; ++mi) hacc[mi] = (f32x4){0.f, 0.f, 0.f, 0.f};
    #pragma unroll
    for (int k32 = 0; k32 < 8; ++k32) {
      int cidx = (k32 << 2) + g;
      bf16x8_t af[4];
      #pragma unroll
      for (int mi = 0; mi < 4; ++mi) {
        int row = mi * 16 + lr;
        af[mi] = *(const bf16x8_t*)(ztile + row * 256 + ((cidx ^ (row & 7)) << 3));
      }
      bf16x8_t bq = *(const bf16x8_t*)(w1 + (size_t)(j * 128 + w * 16 + lr) * 256 + (k32 << 5) + (g << 3));
      #pragma unroll
      for (int mi = 0; mi < 4; ++mi)
        hacc[mi] = __builtin_amdgcn_mfma_f32_16x16x32_bf16(af[mi], bq, hacc[mi], 0, 0, 0);
    }
    // ---- bias + exact GELU -> hbuf[j&1] ----
    unsigned short* hb = hbuf[j & 1];
    {
      int hcol = w * 16 + lr;
      float bb = b1[j * 128 + hcol];
      #pragma unroll
      for (int mi = 0; mi < 4; ++mi) {
        #pragma unroll
        for (int i = 0; i < 4; ++i) {
          float v = hacc[mi][i] + bb;
          v = 0.5f * v * (1.0f + erff(v * 0.70710678118654752f));
          hb[(mi * 16 + g * 4 + i) * 136 + hcol] = f2bf(v);
        }
      }
    }
    __syncthreads();
    // ---- MLP2: out cols [w*32,+32) += h_j @ w2_j^T ----
    #pragma unroll
    for (int ks = 0; ks < 4; ++ks) {
      int kb = (ks << 5) + (g << 3);
      bf16x8_t pf[4], bq2[2];
      #pragma unroll
      for (int mi = 0; mi < 4; ++mi)
        pf[mi] = *(const bf16x8_t*)(hb + (mi * 16 + lr) * 136 + kb);
      #pragma unroll
      for (int ni = 0; ni < 2; ++ni)
        bq2[ni] = *(const bf16x8_t*)(w2 + (size_t)(w * 32 + ni * 16 + lr) * 1024 + j * 128 + kb);
      #pragma unroll
      for (int mi = 0; mi < 4; ++mi)
        #pragma unroll
        for (int ni = 0; ni < 2; ++ni)
          acc[mi][ni] = __builtin_amdgcn_mfma_f32_16x16x32_bf16(pf[mi], bq2[ni], acc[mi][ni], 0, 0, 0);
    }
    // no trailing barrier: hbuf double-buffer makes next j's write race-free
  }

  // ---- epilogue: stg[col][row] bf16 (XOR rows, aliases ztile), then NCHW + x1 + b2 ----
  unsigned short* stg = ztile;
  #pragma unroll
  for (int mi = 0; mi < 4; ++mi)
    #pragma unroll
    for (int ni = 0; ni < 2; ++ni) {
      int cl = w * 32 + ni * 16 + lr;
      int rl = mi * 16 + g * 4;
      f32x4 a = acc[mi][ni];
      #pragma unroll
      for (int i = 0; i < 4; ++i)
        stg[cl * 64 + ((rl + i) ^ ((cl & 7) << 3))] = f2bf(a[i]);
    }
  __syncthreads();
  int c = tid >> 1;                              // output channel 0..255
  int half = tid & 1;
  int b = m0 >> 14;
  int pix0 = (m0 & 16383) + half * 32;
  size_t gbase = ((size_t)b * 256 + c) * 16384 + pix0;
  const unsigned short* xrow = x1 + gbase;
  float* orow = outp + gbase;
  float bb = b2[c];
  #pragma unroll
  for (int jj2 = 0; jj2 < 4; ++jj2) {
    int jj = half * 4 + jj2;                     // 8-row chunk index
    bf16x8_t sv = *(const bf16x8_t*)(stg + c * 64 + ((jj ^ (c & 7)) << 3));
    bf16x8_t xv = *(const bf16x8_t*)(xrow + jj2 * 8);
    #pragma unroll
    for (int e = 0; e < 8; ++e)
      orow[jj2 * 8 + e] = bf2f((unsigned short)sv[e]) + bf2f((unsigned short)xv[e]) + bb;
  }
}

// ---------------- MFMA windowed attention: one window per block, 4 waves, 2 heads/wave ----------------
// qt-sliced: per 16-row q-slice do S -> softmax -> PV, so the P LDS bounce is only [16][72]/wave.
__global__ __launch_bounds__(256, 4) void attn_kernel(const unsigned short* __restrict__ qg,
    const unsigned short* __restrict__ kg, const unsigned short* __restrict__ vt,
    const float* __restrict__ rpb, unsigned short* __restrict__ og) {
  __shared__ float rpbf[1800];
  __shared__ unsigned short pbuf[4][16 * 72];
  // XCD-bijective swizzle: 2048 blocks, 8 XCDs -> each image (256 windows) on one XCD.
  int wi = (blockIdx.x & 7) * 256 + (blockIdx.x >> 3);
  int b = wi >> 8, wh = (wi >> 4) & 15, ww = wi & 15;
  int tid = threadIdx.x;
  int w = tid >> 6, lane = tid & 63;
  int g = lane >> 4, lr = lane & 15;
  for (int idx = tid; idx < 1800; idx += 256) rpbf[idx] = rpb[idx];
  __syncthreads();

  int rowpix = (wh * 8) * 128 + ww * 8;
  size_t ibase = ((size_t)b << 14) + rowpix;
  unsigned short* pb = pbuf[w];
  const float scale = 0.17677669529663689f;

  #pragma unroll 1
  for (int hh = 0; hh < 2; ++hh) {
    int h = w * 2 + hh;
    bf16x8_t qf[4], kf[4];
    #pragma unroll
    for (int t = 0; t < 4; ++t) {
      size_t tok = ibase + (size_t)(t * 2 + (lr >> 3)) * 128 + (lr & 7);
      qf[t] = *(const bf16x8_t*)(qg + tok * 256 + h * 32 + g * 8);
      kf[t] = *(const bf16x8_t*)(kg + tok * 256 + h * 32 + g * 8);
    }
    bf16x8_t vfr[2][2];
    #pragma unroll
    for (int ks = 0; ks < 2; ++ks)
      #pragma unroll
      for (int dt = 0; dt < 2; ++dt) {
        size_t plane = (size_t)b * 256 + h * 32 + dt * 16 + lr;
        vfr[ks][dt] = *(const bf16x8_t*)(vt + (plane << 14) + rowpix + (size_t)(ks * 4 + g) * 128);
      }
    const float* rb = &rpbf[h * 225];

    #pragma unroll 1
    for (int qt = 0; qt < 4; ++qt) {
      f32x4 sacc[4];
      #pragma unroll
      for (int kt = 0; kt < 4; ++kt)
        sacc[kt] = __builtin_amdgcn_mfma_f32_16x16x32_bf16(qf[qt], kf[kt],
                     (f32x4){0.f, 0.f, 0.f, 0.f}, 0, 0, 0);
      float sums[4];
      #pragma unroll
      for (int i = 0; i < 4; ++i) {
        int q = qt * 16 + g * 4 + i;
        int il = q >> 3, jl = q & 7;
        float v[4];
        #pragma unroll
        for (int kt = 0; kt < 4; ++kt) {
          int kv = kt * 16 + lr;
          v[kt] = sacc[kt][i] * scale + rb[(il - (kv >> 3) + 7) * 15 + (jl - (kv & 7) + 7)];
        }
        float mx = fmaxf(fmaxf(v[0], v[1]), fmaxf(v[2], v[3]));
        mx = fmaxf(mx, __shfl_xor(mx, 1));
        mx = fmaxf(mx, __shfl_xor(mx, 2));
        mx = fmaxf(mx, __shfl_xor(mx, 4));
        mx = fmaxf(mx, __shfl_xor(mx, 8));
        float sm = 0.f;
        #pragma unroll
        for (int kt = 0; kt < 4; ++kt) { v[kt] = __expf(v[kt] - mx); sm += v[kt]; }
        sm += __shfl_xor(sm, 1);
        sm += __shfl_xor(sm, 2);
        sm += __shfl_xor(sm, 4);
        sm += __shfl_xor(sm, 8);
        sums[i] = sm;
        #pragma unroll
        for (int kt = 0; kt < 4; ++kt)
          pb[(g * 4 + i) * 72 + kt * 16 + lr] = f2bf(v[kt]);
      }
      f32x4 oacc[2] = {(f32x4){0.f, 0.f, 0.f, 0.f}, (f32x4){0.f, 0.f, 0.f, 0.f}};
      #pragma unroll
      for (int ks = 0; ks < 2; ++ks) {
        bf16x8_t pf = *(const bf16x8_t*)(pb + lr * 72 + ks * 32 + g * 8);
        oacc[0] = __builtin_amdgcn_mfma_f32_16x16x32_bf16(pf, vfr[ks][0], oacc[0], 0, 0, 0);
        oacc[1] = __builtin_amdgcn_mfma_f32_16x16x32_bf16(pf, vfr[ks][1], oacc[1], 0, 0, 0);
      }
      #pragma unroll
      for (int i = 0; i < 4; ++i) {
        int q = qt * 16 + g * 4 + i;
        float inv = 1.0f / sums[i];
        size_t tok = ibase + (size_t)(q >> 3) * 128 + (q & 7);
        og[tok * 256 + h * 32 + lr] = f2bf(oacc[0][i] * inv);
        og[tok * 256 + h * 32 + 16 + lr] = f2bf(oacc[1][i] * inv);
      }
    }
  }
}

// ---------------- depthwise 7x7 conv (bf16 in/out, fp32 math), pad 3, + bias ----------------
__global__ __launch_bounds__(256) void dwconv_kernel(const unsigned short* __restrict__ x1,
    const float* __restrict__ w, const float* __restrict__ bias, unsigned short* __restrict__ outp) {
  int bc = blockIdx.y;                  // 0..2047 (b*256 + c)
  int c = bc & 255;
  int y0 = blockIdx.x << 6;             // 0 or 64
  __shared__ unsigned short tile[70 * 144];
  __shared__ float wf[49];
  const unsigned short* plane = x1 + ((size_t)bc << 14);
  int tid = threadIdx.x;

  for (int idx = tid; idx < 70 * 16; idx += 256) {
    int row = idx >> 4, ch = idx & 15;
    int gy = y0 - 3 + row;
    bf16x8_t v = (bf16x8_t){0, 0, 0, 0, 0, 0, 0, 0};
    if (gy >= 0 && gy < 128) v = *(const bf16x8_t*)(plane + gy * 128 + ch * 8);
    *(bf16x8_t*)(&tile[row * 144 + 8 + ch * 8]) = v;
  }
  for (int idx = tid; idx < 70 * 6; idx += 256) {
    int row = idx / 6, e = idx % 6;
    int col = (e < 3) ? (5 + e) : (133 + e);
    tile[row * 144 + col] = 0;
  }
  if (tid < 49) wf[tid] = w[c * 49 + tid];
  __syncthreads();

  int r = tid >> 2;
  int c0 = (tid & 3) << 5;
  float acc[32];
  float bb = bias[c];
  #pragma unroll
  for (int i = 0; i < 32; ++i) acc[i] = bb;

  #pragma unroll
  for (int u = 0; u < 7; ++u) {
    const unsigned short* rowp = &tile[(r + u) * 144 + c0];
    float f[48];
    #pragma unroll
    for (int k = 0; k < 6; ++k) {
      bf16x8_t v = *(const bf16x8_t*)(rowp + k * 8);
      #pragma unroll
      for (int e = 0; e < 8; ++e) f[k * 8 + e] = bf2f((unsigned short)v[e]);
    }
    #pragma unroll
    for (int t = 0; t < 7; ++t) {
      float wv = wf[u * 7 + t];
      #pragma unroll
      for (int i = 0; i < 32; ++i) acc[i] += f[i + 5 + t] * wv;
    }
  }

  unsigned short* orow = outp + ((size_t)bc << 14) + (size_t)(y0 + r) * 128 + c0;
  #pragma unroll
  for (int k = 0; k < 4; ++k) {
    bf16x8_t v;
    #pragma unroll
    for (int e = 0; e < 8; ++e) v[e] = (short)f2bf(acc[k * 8 + e]);
    *(bf16x8_t*)(orow + k * 8) = v;
  }
}

extern "C" void kernel_launch(void* const* d_in, const int* in_sizes, int n_in,
                              void* d_out, int out_size, void* d_ws, size_t ws_size,
                              hipStream_t stream) {
  const float* x    = (const float*)d_in[0];
  const float* t    = (const float*)d_in[1];
  const float* an_g = (const float*)d_in[2];
  const float* an_b = (const float*)d_in[3];
  const float* wq   = (const float*)d_in[4];
  const float* wk   = (const float*)d_in[5];
  const float* wv   = (const float*)d_in[6];
  const float* wo_w = (const float*)d_in[7];
  const float* wo_b = (const float*)d_in[8];
  const float* rpb  = (const float*)d_in[9];
  const float* dw_w = (const float*)d_in[10];
  const float* dw_b = (const float*)d_in[11];
  const float* fn_g = (const float*)d_in[12];
  const float* fn_b = (const float*)d_in[13];
  const float* w1   = (const float*)d_in[14];
  const float* b1   = (const float*)d_in[15];
  const float* w2   = (const float*)d_in[16];
  const float* b2   = (const float*)d_in[17];
  float* outp = (float*)d_out;

  char* ws = (char*)d_ws;
  const size_t MB = 1024ull * 1024ull;
  float* gvec = (float*)ws;                                   // 32 KB
  unsigned short* wbf = (unsigned short*)(ws + 32768);        // 1.5 MiB
  unsigned short* P = (unsigned short*)(ws + 2 * MB);         // 64 MiB: y -> o -> z
  unsigned short* Q = (unsigned short*)(ws + 66 * MB);        // 64 MiB: q -> y2
  unsigned short* R = (unsigned short*)(ws + 130 * MB);       // 64 MiB: k -> x1 (persists)
  // d_out (128 MiB) scratch regions, both dead before gemm_mlp rewrites d_out:
  unsigned short* xbf  = (unsigned short*)d_out;                      // [0,64) MiB bf16 copy of x
  unsigned short* vbuf = (unsigned short*)((char*)d_out + 64 * MB);   // [64,128) MiB v NCHW bf16

  unsigned short* wq_bf = wbf;
  unsigned short* wk_bf = wbf + 65536;
  unsigned short* wv_bf = wbf + 131072;
  unsigned short* wo_bf = wbf + 196608;
  unsigned short* w1_bf = wbf + 262144;
  unsigned short* w2_bf = wbf + 524288;

  tvec_kernel<<<dim3(8, 4), 256, 0, stream>>>(t, an_g, an_b, fn_g, fn_b, gvec);
  wconv_kernel<<<3072, 256, 0, stream>>>(wq, wk, wv, wo_w, w1, w2, wbf);

  // y = rms_film(x) -> P ; also xbf = bf16(x) NCHW
  film_kernel<0, 1><<<2048, 256, 0, stream>>>(x, gvec, 0, P, xbf);

  // q,k pixel-major; v NCHW bf16 (separate GEMMs — fused variant regressed, round 7)
  gemm_kernel<0><<<dim3(1024, 2), 256, 0, stream>>>(P, wq_bf, nullptr, Q, 256, 256);
  gemm_kernel<0><<<dim3(1024, 2), 256, 0, stream>>>(P, wk_bf, nullptr, R, 256, 256);
  gemm_t_kernel<<<dim3(1024, 2), 256, 0, stream>>>(P, wv_bf, vbuf);

  // windowed attention (MFMA) -> o (P; y dead)
  attn_kernel<<<2048, 256, 0, stream>>>(Q, R, vbuf, rpb, P);

  // WO fused: x1 = bf16(xbf + o@wo^T + wo_b) NCHW -> R (k dead)
  gemm_wof_kernel<<<dim3(1024, 2), 256, 0, stream>>>(P, wo_bf, wo_b, xbf, R);

  // convnext: dwconv (x1 -> y2 in Q) -> film2 (-> z in P)
  dwconv_kernel<<<dim3(2, 2048), 256, 0, stream>>>(R, dw_w, dw_b, Q);
  film_kernel<1, 0><<<2048, 256, 0, stream>>>(Q, gvec, 1, P, nullptr);

  // fused MLP v2 (8 waves, dbuf hbuf, 1 barrier/j) -> d_out
  gemm_mlp_kernel<<<2048, 512, 0, stream>>>(P, w1_bf, b1, w2_bf, b2, R, outp);
}